// Round 5
// baseline (1202.145 us; speedup 1.0000x reference)
//
#include <hip/hip_runtime.h>

#define N_NODES 50000
#define N_EDGES 800000
#define DIM 128
#define NLAYERS 3
#define NCLASSES 6
#define NGRAPHS 64
#define BN_EPS 1e-5f

#define SCAN_BLK 256
#define SCAN_NB ((N_NODES + SCAN_BLK - 1) / SCAN_BLK)  // 196

// GEMM tiling: single-wave blocks, 64x64 tile, 8x8 per lane
#define KB 32
#define TM4 64
#define ROWT ((N_NODES + TM4 - 1) / TM4)  // 782
#define GEMM_NB (ROWT * 2)                // 1564

#define POOL_CHUNKS 8

// ---------------- CSR build ----------------

__global__ void k_count(const int* __restrict__ dst, int* __restrict__ cnt) {
  int e = blockIdx.x * blockDim.x + threadIdx.x;
  if (e < N_EDGES) atomicAdd(&cnt[dst[e]], 1);
}

__global__ void k_scan_a(const int* __restrict__ cnt, int* __restrict__ incl,
                         int* __restrict__ bsum) {
  __shared__ int s[SCAN_BLK];
  int i = blockIdx.x * SCAN_BLK + threadIdx.x;
  int v = (i < N_NODES) ? cnt[i] : 0;
  s[threadIdx.x] = v;
  __syncthreads();
  for (int off = 1; off < SCAN_BLK; off <<= 1) {
    int t = (threadIdx.x >= off) ? s[threadIdx.x - off] : 0;
    __syncthreads();
    s[threadIdx.x] += t;
    __syncthreads();
  }
  if (i < N_NODES) incl[i] = s[threadIdx.x];
  if (threadIdx.x == SCAN_BLK - 1) bsum[blockIdx.x] = s[SCAN_BLK - 1];
}

__global__ void k_scan_b(const int* __restrict__ bsum, int* __restrict__ boff) {
  __shared__ int s[SCAN_BLK];
  int t = threadIdx.x;
  int v = (t < SCAN_NB) ? bsum[t] : 0;
  s[t] = v;
  __syncthreads();
  for (int off = 1; off < SCAN_BLK; off <<= 1) {
    int u = (t >= off) ? s[t - off] : 0;
    __syncthreads();
    s[t] += u;
    __syncthreads();
  }
  boff[t] = s[t] - v;  // exclusive prefix of block sums
}

__global__ void k_scan_c(const int* __restrict__ cnt, const int* __restrict__ incl,
                         const int* __restrict__ boff, int* __restrict__ row_ptr,
                         int* __restrict__ cursor, float* __restrict__ degf) {
  int i = blockIdx.x * SCAN_BLK + threadIdx.x;
  if (i < N_NODES) {
    int ex = incl[i] - cnt[i] + boff[blockIdx.x];
    row_ptr[i] = ex;
    cursor[i] = ex;
    degf[i] = (float)max(cnt[i], 1);
  }
  if (i == 0) row_ptr[N_NODES] = N_EDGES;
}

__global__ void k_fill(const int* __restrict__ src, const int* __restrict__ dst,
                       int* __restrict__ cursor, int* __restrict__ col) {
  int e = blockIdx.x * blockDim.x + threadIdx.x;
  if (e < N_EDGES) {
    int pos = atomicAdd(&cursor[dst[e]], 1);
    col[pos] = src[e];
  }
}

// ---------------- weight pre-transpose ----------------
// Wt[l][k][j]: k<128 -> Wl[l][j][k], k>=128 -> Wr[l][j][k-128]
__global__ void k_wt(const float* __restrict__ Wl, const float* __restrict__ Wr,
                     float* __restrict__ Wt) {
  int i = blockIdx.x * blockDim.x + threadIdx.x;
  if (i >= NLAYERS * 2 * DIM * DIM) return;
  int j = i & (DIM - 1);
  int k = (i >> 7) & 255;
  int l = i >> 15;
  float v;
  if (k < DIM)
    v = Wl[(size_t)l * DIM * DIM + j * DIM + k];
  else
    v = Wr[(size_t)l * DIM * DIM + j * DIM + (k - DIM)];
  Wt[i] = v;
}

// ---------------- per-layer kernels ----------------

// one wave per node; lane holds 2 features (float2); unroll x8.
__global__ void k_gather(const float* __restrict__ xin, const int* __restrict__ row_ptr,
                         const int* __restrict__ col, const float* __restrict__ degf,
                         float* __restrict__ agg) {
  int wid = threadIdx.x >> 6, lane = threadIdx.x & 63;
  int n = blockIdx.x * 4 + wid;
  if (n >= N_NODES) return;
  int beg = row_ptr[n], end = row_ptr[n + 1];
  const float2* x2 = (const float2*)xin;
  float ax = 0.f, ay = 0.f;
  int p = beg;
  for (; p + 7 < end; p += 8) {
    int c[8];
#pragma unroll
    for (int u = 0; u < 8; ++u) c[u] = col[p + u];
    float2 v[8];
#pragma unroll
    for (int u = 0; u < 8; ++u) v[u] = x2[c[u] * 64 + lane];
#pragma unroll
    for (int u = 0; u < 8; ++u) {
      ax += v[u].x;
      ay += v[u].y;
    }
  }
  for (; p < end; ++p) {
    float2 v = x2[col[p] * 64 + lane];
    ax += v.x;
    ay += v.y;
  }
  float inv = 1.0f / degf[n];
  ((float2*)agg)[n * 64 + lane] = make_float2(ax * inv, ay * inv);
}

// Single-wave SGEMM: 64 threads, 64x64 tile, 8x8/lane.
// A staged in LDS (double-buffered, reg-prefetch, NO barriers);
// B (weights) read directly from global (L1/L2-hot broadcast).
__global__ __launch_bounds__(64) void k_gemm4(
    const float* __restrict__ agg, const float* __restrict__ xin,
    const float* __restrict__ Wt, const float* __restrict__ bl,
    float* __restrict__ h) {
  __shared__ float As[2][KB][TM4 + 1];  // 2 x 32 x 65 floats = 16.6 KB
  int bx = blockIdx.x;
  int n0 = (bx >> 1) * TM4;
  int j0 = (bx & 1) * 64;
  int tid = threadIdx.x;
  int lr = tid >> 3;  // 0..7 (row group)
  int lq = tid & 7;   // 0..7 (col group / stage col)

  const float4* W4 = (const float4*)Wt;  // [256][32] float4 rows
  int wjb = (j0 >> 2) + lq;              // float4 col index for b0

  float acc[8][8];
#pragma unroll
  for (int i = 0; i < 8; ++i)
#pragma unroll
    for (int j = 0; j < 8; ++j) acc[i][j] = 0.f;

  float4 pref[8];
  // ---- prologue: load kb=0 A-tile, write to buf 0 ----
  {
    const float* Asrc = agg;
#pragma unroll
    for (int i = 0; i < 8; ++i) {
      int rg = n0 + 8 * i + lr;
      if (rg > N_NODES - 1) rg = N_NODES - 1;
      pref[i] = *(const float4*)(Asrc + (size_t)rg * DIM + 4 * lq);
    }
#pragma unroll
    for (int i = 0; i < 8; ++i) {
      int r = 8 * i + lr;
      As[0][4 * lq + 0][r] = pref[i].x;
      As[0][4 * lq + 1][r] = pref[i].y;
      As[0][4 * lq + 2][r] = pref[i].z;
      As[0][4 * lq + 3][r] = pref[i].w;
    }
  }

#pragma unroll 1
  for (int kb = 0; kb < 8; ++kb) {
    int cur = kb & 1;
    // prefetch next kb's A-tile into registers (hidden under compute)
    if (kb < 7) {
      const float* Asrc = (kb + 1 < 4) ? agg : xin;
      int c0 = ((kb + 1) & 3) * KB;
#pragma unroll
      for (int i = 0; i < 8; ++i) {
        int rg = n0 + 8 * i + lr;
        if (rg > N_NODES - 1) rg = N_NODES - 1;
        pref[i] = *(const float4*)(Asrc + (size_t)rg * DIM + c0 + 4 * lq);
      }
    }
    // compute kb from As[cur] + B from global
#pragma unroll
    for (int kk = 0; kk < KB; ++kk) {
      float a[8], b[8];
      *(float4*)&a[0] = *(const float4*)&As[cur][kk][4 * lr];
      *(float4*)&a[4] = *(const float4*)&As[cur][kk][32 + 4 * lr];
      size_t wrow = (size_t)(kb * KB + kk) * 32;
      *(float4*)&b[0] = W4[wrow + wjb];
      *(float4*)&b[4] = W4[wrow + wjb + 8];
#pragma unroll
      for (int i = 0; i < 8; ++i)
#pragma unroll
        for (int j = 0; j < 8; ++j) acc[i][j] += a[i] * b[j];
    }
    // write prefetched tile into the other buffer
    if (kb < 7) {
#pragma unroll
      for (int i = 0; i < 8; ++i) {
        int r = 8 * i + lr;
        As[cur ^ 1][4 * lq + 0][r] = pref[i].x;
        As[cur ^ 1][4 * lq + 1][r] = pref[i].y;
        As[cur ^ 1][4 * lq + 2][r] = pref[i].z;
        As[cur ^ 1][4 * lq + 3][r] = pref[i].w;
      }
    }
  }

  // ---- epilogue: bias + store ----
  float bv[8];
#pragma unroll
  for (int u = 0; u < 4; ++u) {
    bv[u] = bl[j0 + 4 * lq + u];
    bv[4 + u] = bl[j0 + 32 + 4 * lq + u];
  }
#pragma unroll
  for (int gi = 0; gi < 2; ++gi)
#pragma unroll
    for (int i = 0; i < 4; ++i) {
      int ri = gi * 4 + i;
      int n = n0 + gi * 32 + 4 * lr + i;
      if (n < N_NODES) {
        float o[8];
#pragma unroll
        for (int j = 0; j < 8; ++j) o[j] = acc[ri][j] + bv[j];
        float* dstp = h + (size_t)n * DIM + j0;
        *(float4*)(dstp + 4 * lq) = *(float4*)&o[0];
        *(float4*)(dstp + 32 + 4 * lq) = *(float4*)&o[4];
      }
    }
}

__global__ void k_bn_stats(const float* __restrict__ h, float* __restrict__ sums) {
  int j = threadIdx.x;  // 128 threads = 128 features
  float s = 0.f, q = 0.f;
  for (int n = blockIdx.x; n < N_NODES; n += gridDim.x) {
    float v = h[n * DIM + j];
    s += v;
    q += v * v;
  }
  atomicAdd(&sums[j], s);
  atomicAdd(&sums[DIM + j], q);
}

__global__ void k_bn_apply(const float* __restrict__ h, const float* __restrict__ sums,
                           const float* __restrict__ gamma, const float* __restrict__ beta,
                           float* __restrict__ xout) {
  int i4 = blockIdx.x * blockDim.x + threadIdx.x;
  if (i4 >= N_NODES * DIM / 4) return;
  int j0 = (i4 * 4) & (DIM - 1);
  float4 v = ((const float4*)h)[i4];
  float o[4] = {v.x, v.y, v.z, v.w};
#pragma unroll
  for (int u = 0; u < 4; ++u) {
    int j = j0 + u;
    float mu = sums[j] * (1.0f / N_NODES);
    float var = sums[DIM + j] * (1.0f / N_NODES) - mu * mu;
    float sc = gamma[j] * rsqrtf(var + BN_EPS);
    o[u] = fmaxf((o[u] - mu) * sc + beta[j], 0.f);
  }
  float4 r = {o[0], o[1], o[2], o[3]};
  ((float4*)xout)[i4] = r;
}

// ---------------- pooling + head ----------------

__global__ void k_gbounds(const int* __restrict__ batch, int* __restrict__ gstart) {
  int t = threadIdx.x;
  if (t > NGRAPHS) return;
  if (t == NGRAPHS) {
    gstart[NGRAPHS] = N_NODES;
    return;
  }
  int lo = 0, hi = N_NODES;
  while (lo < hi) {
    int mid = (lo + hi) >> 1;
    if (batch[mid] < t) lo = mid + 1;
    else hi = mid;
  }
  gstart[t] = lo;
}

__global__ void k_pool2(const float* __restrict__ x, const int* __restrict__ gstart,
                        float* __restrict__ pooled) {
  int g = blockIdx.x >> 3;
  int ck = blockIdx.x & 7;
  int s = gstart[g], e = gstart[g + 1];
  int len = e - s;
  int per = (len + POOL_CHUNKS - 1) / POOL_CHUNKS;
  int rs = s + ck * per;
  int re = min(rs + per, e);
  int j = threadIdx.x & 127;
  int rg = threadIdx.x >> 7;  // 0..1
  float acc = 0.f;
  for (int r = rs + rg; r < re; r += 2) acc += x[(size_t)r * DIM + j];
  __shared__ float sred[2][DIM];
  sred[rg][j] = acc;
  __syncthreads();
  if (rg == 0) {
    float v = sred[0][j] + sred[1][j];
    atomicAdd(&pooled[g * DIM + j], v);
  }
}

__global__ void k_head(const float* __restrict__ pooled, const int* __restrict__ gstart,
                       const float* __restrict__ W1, const float* __restrict__ b1,
                       const float* __restrict__ W2, const float* __restrict__ b2,
                       float* __restrict__ out) {
  __shared__ float pm[NGRAPHS * DIM];
  __shared__ float hid[NGRAPHS * 64];
  for (int i = threadIdx.x; i < NGRAPHS * DIM; i += blockDim.x) {
    int g = i >> 7;
    float c = (float)(gstart[g + 1] - gstart[g]);
    pm[i] = pooled[i] / fmaxf(c, 1.0f);
  }
  __syncthreads();
  for (int i = threadIdx.x; i < NGRAPHS * 64; i += blockDim.x) {
    int g = i >> 6, m = i & 63;
    float acc = b1[m];
    for (int k = 0; k < DIM; ++k) acc += pm[g * DIM + k] * W1[m * DIM + k];
    hid[i] = fmaxf(acc, 0.f);
  }
  __syncthreads();
  for (int i = threadIdx.x; i < NGRAPHS * NCLASSES; i += blockDim.x) {
    int g = i / NCLASSES, c = i % NCLASSES;
    float acc = b2[c];
    for (int m = 0; m < 64; ++m) acc += hid[g * 64 + m] * W2[c * 64 + m];
    out[i] = acc;
  }
}

// ---------------- launch ----------------

extern "C" void kernel_launch(void* const* d_in, const int* in_sizes, int n_in,
                              void* d_out, int out_size, void* d_ws, size_t ws_size,
                              hipStream_t stream) {
  const float* x = (const float*)d_in[0];
  const int* edge = (const int*)d_in[1];
  const int* batch = (const int*)d_in[2];
  const float* Wl = (const float*)d_in[3];
  const float* bl = (const float*)d_in[4];
  const float* Wr = (const float*)d_in[5];
  const float* gamma = (const float*)d_in[6];
  const float* beta = (const float*)d_in[7];
  const float* W1 = (const float*)d_in[8];
  const float* b1 = (const float*)d_in[9];
  const float* W2 = (const float*)d_in[10];
  const float* b2 = (const float*)d_in[11];
  float* out = (float*)d_out;

  const int* src = edge;
  const int* dst = edge + N_EDGES;

  char* p = (char*)d_ws;
  auto alloc = [&](size_t bytes) -> void* {
    void* r = (void*)p;
    p += (bytes + 255) & ~(size_t)255;
    return r;
  };
  int* cnt = (int*)alloc(N_NODES * 4);
  int* incl = (int*)alloc(N_NODES * 4);
  int* bsum = (int*)alloc(SCAN_BLK * 4);
  int* boff = (int*)alloc(SCAN_BLK * 4);
  int* row_ptr = (int*)alloc((N_NODES + 1) * 4);
  int* cursor = (int*)alloc(N_NODES * 4);
  int* col = (int*)alloc(N_EDGES * 4);
  float* degf = (float*)alloc(N_NODES * 4);
  float* Wt = (float*)alloc((size_t)NLAYERS * 2 * DIM * DIM * 4);
  float* x_cur = (float*)alloc((size_t)N_NODES * DIM * 4);
  float* agg = (float*)alloc((size_t)N_NODES * DIM * 4);
  float* hbuf = (float*)alloc((size_t)N_NODES * DIM * 4);
  float* sums = (float*)alloc(2 * DIM * 4);
  float* pooled = (float*)alloc(NGRAPHS * DIM * 4);
  int* gstart = (int*)alloc((NGRAPHS + 1) * 4);

  // ---- CSR build + weight transpose + graph bounds ----
  hipMemsetAsync(cnt, 0, N_NODES * 4, stream);
  k_count<<<(N_EDGES + 255) / 256, 256, 0, stream>>>(dst, cnt);
  k_scan_a<<<SCAN_NB, SCAN_BLK, 0, stream>>>(cnt, incl, bsum);
  k_scan_b<<<1, SCAN_BLK, 0, stream>>>(bsum, boff);
  k_scan_c<<<SCAN_NB, SCAN_BLK, 0, stream>>>(cnt, incl, boff, row_ptr, cursor, degf);
  k_fill<<<(N_EDGES + 255) / 256, 256, 0, stream>>>(src, dst, cursor, col);
  k_wt<<<(NLAYERS * 2 * DIM * DIM + 255) / 256, 256, 0, stream>>>(Wl, Wr, Wt);
  k_gbounds<<<1, 128, 0, stream>>>(batch, gstart);

  // ---- layers ----
  const float* xin = x;
  for (int l = 0; l < NLAYERS; ++l) {
    k_gather<<<(N_NODES + 3) / 4, 256, 0, stream>>>(xin, row_ptr, col, degf, agg);
    k_gemm4<<<GEMM_NB, 64, 0, stream>>>(agg, xin, Wt + (size_t)l * 2 * DIM * DIM,
                                        bl + (size_t)l * DIM, hbuf);
    hipMemsetAsync(sums, 0, 2 * DIM * 4, stream);
    k_bn_stats<<<512, DIM, 0, stream>>>(hbuf, sums);
    k_bn_apply<<<(N_NODES * DIM / 4 + 255) / 256, 256, 0, stream>>>(
        hbuf, sums, gamma + (size_t)l * DIM, beta + (size_t)l * DIM, x_cur);
    xin = x_cur;
  }

  // ---- pool + head ----
  hipMemsetAsync(pooled, 0, NGRAPHS * DIM * 4, stream);
  k_pool2<<<NGRAPHS * POOL_CHUNKS, 256, 0, stream>>>(x_cur, gstart, pooled);
  k_head<<<1, 256, 0, stream>>>(pooled, gstart, W1, b1, W2, b2, out);
}

// Round 6
// 489.666 us; speedup vs baseline: 2.4550x; 2.4550x over previous
//
#include <hip/hip_runtime.h>

#define N_NODES 50000
#define N_EDGES 800000
#define DIM 128
#define NLAYERS 3
#define NCLASSES 6
#define NGRAPHS 64
#define BN_EPS 1e-5f

#define SCAN_BLK 256
#define SCAN_NB ((N_NODES + SCAN_BLK - 1) / SCAN_BLK)  // 196

#define POOL_CHUNKS 8

typedef unsigned short ushort_t;
typedef unsigned int uint_t;
using bf16x8 = __attribute__((ext_vector_type(8))) short;
using f32x4 = __attribute__((ext_vector_type(4))) float;

__device__ __forceinline__ float bf2f(ushort_t b) {
  return __uint_as_float(((uint_t)b) << 16);
}
__device__ __forceinline__ ushort_t f2bf(float f) {  // round-to-nearest-even
  uint_t u = __float_as_uint(f);
  u += 0x7fffu + ((u >> 16) & 1u);
  return (ushort_t)(u >> 16);
}

// ---------------- CSR build ----------------

__global__ void k_count(const int* __restrict__ dst, int* __restrict__ cnt) {
  int e = blockIdx.x * blockDim.x + threadIdx.x;
  if (e < N_EDGES) atomicAdd(&cnt[dst[e]], 1);
}

__global__ void k_scan_a(const int* __restrict__ cnt, int* __restrict__ incl,
                         int* __restrict__ bsum) {
  __shared__ int s[SCAN_BLK];
  int i = blockIdx.x * SCAN_BLK + threadIdx.x;
  int v = (i < N_NODES) ? cnt[i] : 0;
  s[threadIdx.x] = v;
  __syncthreads();
  for (int off = 1; off < SCAN_BLK; off <<= 1) {
    int t = (threadIdx.x >= off) ? s[threadIdx.x - off] : 0;
    __syncthreads();
    s[threadIdx.x] += t;
    __syncthreads();
  }
  if (i < N_NODES) incl[i] = s[threadIdx.x];
  if (threadIdx.x == SCAN_BLK - 1) bsum[blockIdx.x] = s[SCAN_BLK - 1];
}

__global__ void k_scan_b(const int* __restrict__ bsum, int* __restrict__ boff) {
  __shared__ int s[SCAN_BLK];
  int t = threadIdx.x;
  int v = (t < SCAN_NB) ? bsum[t] : 0;
  s[t] = v;
  __syncthreads();
  for (int off = 1; off < SCAN_BLK; off <<= 1) {
    int u = (t >= off) ? s[t - off] : 0;
    __syncthreads();
    s[t] += u;
    __syncthreads();
  }
  boff[t] = s[t] - v;
}

__global__ void k_scan_c(const int* __restrict__ cnt, const int* __restrict__ incl,
                         const int* __restrict__ boff, int* __restrict__ row_ptr,
                         int* __restrict__ cursor, float* __restrict__ degf) {
  int i = blockIdx.x * SCAN_BLK + threadIdx.x;
  if (i < N_NODES) {
    int ex = incl[i] - cnt[i] + boff[blockIdx.x];
    row_ptr[i] = ex;
    cursor[i] = ex;
    degf[i] = (float)max(cnt[i], 1);
  }
  if (i == 0) row_ptr[N_NODES] = N_EDGES;
}

__global__ void k_fill(const int* __restrict__ src, const int* __restrict__ dst,
                       int* __restrict__ cursor, int* __restrict__ col) {
  int e = blockIdx.x * blockDim.x + threadIdx.x;
  if (e < N_EDGES) {
    int pos = atomicAdd(&cursor[dst[e]], 1);
    col[pos] = src[e];
  }
}

// ---------------- weight prep: split hi/lo bf16, frag-order permute ----------------
// W2 layout (ushort): [l][kstep 0..7][part 0..1][q 0..3][c 0..127][kk8 0..7]
// k_global = kstep*32 + q*8 + kk8; k<128 -> Wl[l][c][k], else Wr[l][c][k-128]
__global__ void k_wt2(const float* __restrict__ Wl, const float* __restrict__ Wr,
                      ushort_t* __restrict__ W2) {
  int i = blockIdx.x * blockDim.x + threadIdx.x;  // 3*8*4*128 = 12288
  if (i >= NLAYERS * 8 * 4 * 128) return;
  int c = i & 127;
  int q = (i >> 7) & 3;
  int ks = (i >> 9) & 7;
  int l = i >> 12;
  int kbase = ks * 32 + q * 8;
  size_t obase = (size_t)l * 65536 + ks * 8192 + q * 1024 + c * 8;
#pragma unroll
  for (int kk = 0; kk < 8; ++kk) {
    int k = kbase + kk;
    float w = (k < DIM) ? Wl[(size_t)l * DIM * DIM + c * DIM + k]
                        : Wr[(size_t)l * DIM * DIM + c * DIM + (k - DIM)];
    ushort_t hi = f2bf(w);
    float lo = w - bf2f(hi);
    W2[obase + kk] = hi;
    W2[obase + 4096 + kk] = f2bf(lo);  // part 1 offset = 4*1024
  }
}

// fp32 -> bf16 convert (input x)
__global__ void k_tobf16(const float* __restrict__ x, ushort_t* __restrict__ xb) {
  int i4 = blockIdx.x * blockDim.x + threadIdx.x;
  if (i4 >= N_NODES * DIM / 4) return;
  float4 v = ((const float4*)x)[i4];
  ushort4 o;
  o.x = f2bf(v.x);
  o.y = f2bf(v.y);
  o.z = f2bf(v.z);
  o.w = f2bf(v.w);
  ((ushort4*)xb)[i4] = o;
}

// ---------------- per-layer kernels ----------------

// one wave per node; lane holds 2 bf16 features (4 B); unroll x8.
__global__ void k_gather2(const ushort_t* __restrict__ xb, const int* __restrict__ row_ptr,
                          const int* __restrict__ col, const float* __restrict__ degf,
                          ushort_t* __restrict__ aggb) {
  int wid = threadIdx.x >> 6, lane = threadIdx.x & 63;
  int n = blockIdx.x * 4 + wid;
  if (n >= N_NODES) return;
  int beg = row_ptr[n], end = row_ptr[n + 1];
  const uint_t* x1 = (const uint_t*)xb;  // row = 64 uints
  float ax = 0.f, ay = 0.f;
  int p = beg;
  for (; p + 7 < end; p += 8) {
    int c[8];
#pragma unroll
    for (int u = 0; u < 8; ++u) c[u] = col[p + u];
    uint_t v[8];
#pragma unroll
    for (int u = 0; u < 8; ++u) v[u] = x1[c[u] * 64 + lane];
#pragma unroll
    for (int u = 0; u < 8; ++u) {
      ax += bf2f((ushort_t)(v[u] & 0xffffu));
      ay += bf2f((ushort_t)(v[u] >> 16));
    }
  }
  for (; p < end; ++p) {
    uint_t v = x1[col[p] * 64 + lane];
    ax += bf2f((ushort_t)(v & 0xffffu));
    ay += bf2f((ushort_t)(v >> 16));
  }
  float inv = 1.0f / degf[n];
  uint_t o = (uint_t)f2bf(ax * inv) | ((uint_t)f2bf(ay * inv) << 16);
  ((uint_t*)aggb)[n * 64 + lane] = o;
}

// MFMA GEMM: h[n][j] = bl[j] + sum_k A[n][k]*W[k][j], A=[aggb|xb] bf16, W=hi+lo bf16.
// 256 threads = 4 waves, 16 rows/wave, 64 rows/block. 16x16x32 MFMA.
__global__ __launch_bounds__(256) void k_mfma(
    const ushort_t* __restrict__ aggb, const ushort_t* __restrict__ xb,
    const ushort_t* __restrict__ W2l, const float* __restrict__ bl,
    float* __restrict__ h) {
  __shared__ ushort_t Bs[8192];   // 16 KB: [part][q][c][8]
  __shared__ float Es[4][16][65];  // per-wave epilogue transpose

  int tid = threadIdx.x;
  int wave = tid >> 6, lane = tid & 63;
  int rw = blockIdx.x * 64 + wave * 16;
  int lr = lane & 15;   // frag row / frag col
  int q = lane >> 4;    // 0..3 (k-chunk)
  int rowA = rw + lr;
  if (rowA > N_NODES - 1) rowA = N_NODES - 1;  // clamp; stores guarded

  f32x4 acc[8];
#pragma unroll
  for (int c = 0; c < 8; ++c) acc[c] = (f32x4){0.f, 0.f, 0.f, 0.f};

#pragma unroll 1
  for (int ks = 0; ks < 8; ++ks) {
    // stage this kstep's weights (hi+lo) : 16 KB linear copy
    const uint4* wsrc = (const uint4*)(W2l + (size_t)ks * 8192);
#pragma unroll
    for (int it = 0; it < 4; ++it) {
      int idx = it * 256 + tid;
      ((uint4*)Bs)[idx] = wsrc[idx];
    }
    __syncthreads();
    const ushort_t* Asrc = (ks < 4) ? aggb : xb;
    int koff = (ks & 3) * 32 + q * 8;
    bf16x8 af = *(const bf16x8*)(Asrc + (size_t)rowA * DIM + koff);
#pragma unroll
    for (int cf = 0; cf < 8; ++cf) {
      int ci = cf * 16 + lr;
      bf16x8 bh = *(const bf16x8*)(Bs + (q * 128 + ci) * 8);
      bf16x8 bo = *(const bf16x8*)(Bs + 4096 + (q * 128 + ci) * 8);
      acc[cf] = __builtin_amdgcn_mfma_f32_16x16x32_bf16(af, bh, acc[cf], 0, 0, 0);
      acc[cf] = __builtin_amdgcn_mfma_f32_16x16x32_bf16(af, bo, acc[cf], 0, 0, 0);
    }
    __syncthreads();
  }

  // epilogue: C frag (col=lane&15, row=q*4+i) -> LDS transpose -> coalesced store
#pragma unroll
  for (int colhalf = 0; colhalf < 2; ++colhalf) {
#pragma unroll
    for (int cf2 = 0; cf2 < 4; ++cf2) {
      f32x4 a = acc[colhalf * 4 + cf2];
#pragma unroll
      for (int i = 0; i < 4; ++i) Es[wave][q * 4 + i][cf2 * 16 + lr] = a[i];
    }
    __syncthreads();
#pragma unroll
    for (int it = 0; it < 4; ++it) {
      int idx = it * 64 + lane;
      int r = idx >> 4, c4 = idx & 15;
      int n = rw + r;
      if (n < N_NODES) {
        int j = colhalf * 64 + c4 * 4;
        float4 v = *(float4*)&Es[wave][r][c4 * 4];
        v.x += bl[j];
        v.y += bl[j + 1];
        v.z += bl[j + 2];
        v.w += bl[j + 3];
        *(float4*)(h + (size_t)n * DIM + j) = v;
      }
    }
    __syncthreads();
  }
}

__global__ void k_bn_stats(const float* __restrict__ h, float* __restrict__ sums) {
  int j = threadIdx.x;  // 128
  float s = 0.f, q = 0.f;
  for (int n = blockIdx.x; n < N_NODES; n += gridDim.x) {
    float v = h[n * DIM + j];
    s += v;
    q += v * v;
  }
  atomicAdd(&sums[j], s);
  atomicAdd(&sums[DIM + j], q);
}

// normalize + relu -> bf16
__global__ void k_bn_apply(const float* __restrict__ h, const float* __restrict__ sums,
                           const float* __restrict__ gamma, const float* __restrict__ beta,
                           ushort_t* __restrict__ xb) {
  int i4 = blockIdx.x * blockDim.x + threadIdx.x;
  if (i4 >= N_NODES * DIM / 4) return;
  int j0 = (i4 * 4) & (DIM - 1);
  float4 v = ((const float4*)h)[i4];
  float o[4] = {v.x, v.y, v.z, v.w};
  ushort4 r;
#pragma unroll
  for (int u = 0; u < 4; ++u) {
    int j = j0 + u;
    float mu = sums[j] * (1.0f / N_NODES);
    float var = sums[DIM + j] * (1.0f / N_NODES) - mu * mu;
    float sc = gamma[j] * rsqrtf(var + BN_EPS);
    o[u] = fmaxf((o[u] - mu) * sc + beta[j], 0.f);
  }
  r.x = f2bf(o[0]);
  r.y = f2bf(o[1]);
  r.z = f2bf(o[2]);
  r.w = f2bf(o[3]);
  ((ushort4*)xb)[i4] = r;
}

// ---------------- pooling + head ----------------

__global__ void k_gbounds(const int* __restrict__ batch, int* __restrict__ gstart) {
  int t = threadIdx.x;
  if (t > NGRAPHS) return;
  if (t == NGRAPHS) {
    gstart[NGRAPHS] = N_NODES;
    return;
  }
  int lo = 0, hi = N_NODES;
  while (lo < hi) {
    int mid = (lo + hi) >> 1;
    if (batch[mid] < t) lo = mid + 1;
    else hi = mid;
  }
  gstart[t] = lo;
}

__global__ void k_pool2(const ushort_t* __restrict__ xb, const int* __restrict__ gstart,
                        float* __restrict__ pooled) {
  int g = blockIdx.x >> 3;
  int ck = blockIdx.x & 7;
  int s = gstart[g], e = gstart[g + 1];
  int len = e - s;
  int per = (len + POOL_CHUNKS - 1) / POOL_CHUNKS;
  int rs = s + ck * per;
  int re = min(rs + per, e);
  int j2 = threadIdx.x & 63;   // uint (2 feats)
  int rg = threadIdx.x >> 6;   // 0..3
  const uint_t* x1 = (const uint_t*)xb;
  float ax = 0.f, ay = 0.f;
  for (int r = rs + rg; r < re; r += 4) {
    uint_t v = x1[(size_t)r * 64 + j2];
    ax += bf2f((ushort_t)(v & 0xffffu));
    ay += bf2f((ushort_t)(v >> 16));
  }
  __shared__ float sred[4][DIM];
  sred[rg][2 * j2] = ax;
  sred[rg][2 * j2 + 1] = ay;
  __syncthreads();
  if (rg < 2) {
    int j = rg * 64 + j2;  // feature index 0..127 handled by first 128 threads
    float v = sred[0][j] + sred[1][j] + sred[2][j] + sred[3][j];
    atomicAdd(&pooled[g * DIM + j], v);
  }
}

__global__ void k_head(const float* __restrict__ pooled, const int* __restrict__ gstart,
                       const float* __restrict__ W1, const float* __restrict__ b1,
                       const float* __restrict__ W2, const float* __restrict__ b2,
                       float* __restrict__ out) {
  __shared__ float pm[NGRAPHS * DIM];
  __shared__ float hid[NGRAPHS * 64];
  for (int i = threadIdx.x; i < NGRAPHS * DIM; i += blockDim.x) {
    int g = i >> 7;
    float c = (float)(gstart[g + 1] - gstart[g]);
    pm[i] = pooled[i] / fmaxf(c, 1.0f);
  }
  __syncthreads();
  for (int i = threadIdx.x; i < NGRAPHS * 64; i += blockDim.x) {
    int g = i >> 6, m = i & 63;
    float acc = b1[m];
    for (int k = 0; k < DIM; ++k) acc += pm[g * DIM + k] * W1[m * DIM + k];
    hid[i] = fmaxf(acc, 0.f);
  }
  __syncthreads();
  for (int i = threadIdx.x; i < NGRAPHS * NCLASSES; i += blockDim.x) {
    int g = i / NCLASSES, c = i % NCLASSES;
    float acc = b2[c];
    for (int m = 0; m < 64; ++m) acc += hid[g * 64 + m] * W2[c * 64 + m];
    out[i] = acc;
  }
}

// ---------------- launch ----------------

extern "C" void kernel_launch(void* const* d_in, const int* in_sizes, int n_in,
                              void* d_out, int out_size, void* d_ws, size_t ws_size,
                              hipStream_t stream) {
  const float* x = (const float*)d_in[0];
  const int* edge = (const int*)d_in[1];
  const int* batch = (const int*)d_in[2];
  const float* Wl = (const float*)d_in[3];
  const float* bl = (const float*)d_in[4];
  const float* Wr = (const float*)d_in[5];
  const float* gamma = (const float*)d_in[6];
  const float* beta = (const float*)d_in[7];
  const float* W1 = (const float*)d_in[8];
  const float* b1 = (const float*)d_in[9];
  const float* W2 = (const float*)d_in[10];
  const float* b2 = (const float*)d_in[11];
  float* out = (float*)d_out;

  const int* src = edge;
  const int* dst = edge + N_EDGES;

  char* p = (char*)d_ws;
  auto alloc = [&](size_t bytes) -> void* {
    void* r = (void*)p;
    p += (bytes + 255) & ~(size_t)255;
    return r;
  };
  int* cnt = (int*)alloc(N_NODES * 4);
  int* incl = (int*)alloc(N_NODES * 4);
  int* bsum = (int*)alloc(SCAN_BLK * 4);
  int* boff = (int*)alloc(SCAN_BLK * 4);
  int* row_ptr = (int*)alloc((N_NODES + 1) * 4);
  int* cursor = (int*)alloc(N_NODES * 4);
  int* col = (int*)alloc(N_EDGES * 4);
  float* degf = (float*)alloc(N_NODES * 4);
  ushort_t* W2b = (ushort_t*)alloc((size_t)NLAYERS * 65536 * 2);
  ushort_t* xb0 = (ushort_t*)alloc((size_t)N_NODES * DIM * 2);
  ushort_t* xb_cur = (ushort_t*)alloc((size_t)N_NODES * DIM * 2);
  ushort_t* aggb = (ushort_t*)alloc((size_t)N_NODES * DIM * 2);
  float* hbuf = (float*)alloc((size_t)N_NODES * DIM * 4);
  float* sums = (float*)alloc(2 * DIM * 4);
  float* pooled = (float*)alloc(NGRAPHS * DIM * 4);
  int* gstart = (int*)alloc((NGRAPHS + 1) * 4);

  // ---- CSR build + weight prep + graph bounds + x->bf16 ----
  hipMemsetAsync(cnt, 0, N_NODES * 4, stream);
  k_count<<<(N_EDGES + 255) / 256, 256, 0, stream>>>(dst, cnt);
  k_scan_a<<<SCAN_NB, SCAN_BLK, 0, stream>>>(cnt, incl, bsum);
  k_scan_b<<<1, SCAN_BLK, 0, stream>>>(bsum, boff);
  k_scan_c<<<SCAN_NB, SCAN_BLK, 0, stream>>>(cnt, incl, boff, row_ptr, cursor, degf);
  k_fill<<<(N_EDGES + 255) / 256, 256, 0, stream>>>(src, dst, cursor, col);
  k_wt2<<<(NLAYERS * 8 * 4 * 128 + 255) / 256, 256, 0, stream>>>(Wl, Wr, W2b);
  k_gbounds<<<1, 128, 0, stream>>>(batch, gstart);
  k_tobf16<<<(N_NODES * DIM / 4 + 255) / 256, 256, 0, stream>>>(x, xb0);

  // ---- layers ----
  const ushort_t* xin = xb0;
  for (int l = 0; l < NLAYERS; ++l) {
    k_gather2<<<(N_NODES + 3) / 4, 256, 0, stream>>>(xin, row_ptr, col, degf, aggb);
    k_mfma<<<(N_NODES + 63) / 64, 256, 0, stream>>>(
        aggb, xin, W2b + (size_t)l * 65536, bl + (size_t)l * DIM, hbuf);
    hipMemsetAsync(sums, 0, 2 * DIM * 4, stream);
    k_bn_stats<<<512, DIM, 0, stream>>>(hbuf, sums);
    k_bn_apply<<<(N_NODES * DIM / 4 + 255) / 256, 256, 0, stream>>>(
        hbuf, sums, gamma + (size_t)l * DIM, beta + (size_t)l * DIM, xb_cur);
    xin = xb_cur;
  }

  // ---- pool + head ----
  hipMemsetAsync(pooled, 0, NGRAPHS * DIM * 4, stream);
  k_pool2<<<NGRAPHS * POOL_CHUNKS, 256, 0, stream>>>(xb_cur, gstart, pooled);
  k_head<<<1, 256, 0, stream>>>(pooled, gstart, W1, b1, W2, b2, out);
}

// Round 7
// 425.198 us; speedup vs baseline: 2.8273x; 1.1516x over previous
//
#include <hip/hip_runtime.h>

#define N_NODES 50000
#define N_EDGES 800000
#define DIM 128
#define NLAYERS 3
#define NCLASSES 6
#define NGRAPHS 64
#define BN_EPS 1e-5f

#define SCAN_BLK 256
#define SCAN_NB ((N_NODES + SCAN_BLK - 1) / SCAN_BLK)  // 196

#define POOL_CHUNKS 8

typedef unsigned short ushort_t;
typedef unsigned int uint_t;
using bf16x8 = __attribute__((ext_vector_type(8))) short;
using f32x4 = __attribute__((ext_vector_type(4))) float;

__device__ __forceinline__ float bf2f(ushort_t b) {
  return __uint_as_float(((uint_t)b) << 16);
}
__device__ __forceinline__ ushort_t f2bf(float f) {  // round-to-nearest-even
  uint_t u = __float_as_uint(f);
  u += 0x7fffu + ((u >> 16) & 1u);
  return (ushort_t)(u >> 16);
}

// ---------------- CSR build ----------------

__global__ void k_count(const int* __restrict__ dst, int* __restrict__ cnt) {
  int e = blockIdx.x * blockDim.x + threadIdx.x;
  if (e < N_EDGES) atomicAdd(&cnt[dst[e]], 1);
}

__global__ void k_scan_a(const int* __restrict__ cnt, int* __restrict__ incl,
                         int* __restrict__ bsum) {
  __shared__ int s[SCAN_BLK];
  int i = blockIdx.x * SCAN_BLK + threadIdx.x;
  int v = (i < N_NODES) ? cnt[i] : 0;
  s[threadIdx.x] = v;
  __syncthreads();
  for (int off = 1; off < SCAN_BLK; off <<= 1) {
    int t = (threadIdx.x >= off) ? s[threadIdx.x - off] : 0;
    __syncthreads();
    s[threadIdx.x] += t;
    __syncthreads();
  }
  if (i < N_NODES) incl[i] = s[threadIdx.x];
  if (threadIdx.x == SCAN_BLK - 1) bsum[blockIdx.x] = s[SCAN_BLK - 1];
}

__global__ void k_scan_b(const int* __restrict__ bsum, int* __restrict__ boff) {
  __shared__ int s[SCAN_BLK];
  int t = threadIdx.x;
  int v = (t < SCAN_NB) ? bsum[t] : 0;
  s[t] = v;
  __syncthreads();
  for (int off = 1; off < SCAN_BLK; off <<= 1) {
    int u = (t >= off) ? s[t - off] : 0;
    __syncthreads();
    s[t] += u;
    __syncthreads();
  }
  boff[t] = s[t] - v;
}

__global__ void k_scan_c(const int* __restrict__ cnt, const int* __restrict__ incl,
                         const int* __restrict__ boff, int* __restrict__ row_ptr,
                         int* __restrict__ cursor, float* __restrict__ degf) {
  int i = blockIdx.x * SCAN_BLK + threadIdx.x;
  if (i < N_NODES) {
    int ex = incl[i] - cnt[i] + boff[blockIdx.x];
    row_ptr[i] = ex;
    cursor[i] = ex;
    degf[i] = (float)max(cnt[i], 1);
  }
  if (i == 0) row_ptr[N_NODES] = N_EDGES;
}

__global__ void k_fill(const int* __restrict__ src, const int* __restrict__ dst,
                       int* __restrict__ cursor, int* __restrict__ col) {
  int e = blockIdx.x * blockDim.x + threadIdx.x;
  if (e < N_EDGES) {
    int pos = atomicAdd(&cursor[dst[e]], 1);
    col[pos] = src[e];
  }
}

// ---------------- weight prep: split hi/lo bf16, frag-order permute ----------------
// W2 layout (ushort): [l][kstep 0..7][part 0..1][q 0..3][c 0..127][kk8 0..7]
__global__ void k_wt2(const float* __restrict__ Wl, const float* __restrict__ Wr,
                      ushort_t* __restrict__ W2) {
  int i = blockIdx.x * blockDim.x + threadIdx.x;  // 3*8*4*128 = 12288
  if (i >= NLAYERS * 8 * 4 * 128) return;
  int c = i & 127;
  int q = (i >> 7) & 3;
  int ks = (i >> 9) & 7;
  int l = i >> 12;
  int kbase = ks * 32 + q * 8;
  size_t obase = (size_t)l * 65536 + ks * 8192 + q * 1024 + c * 8;
#pragma unroll
  for (int kk = 0; kk < 8; ++kk) {
    int k = kbase + kk;
    float w = (k < DIM) ? Wl[(size_t)l * DIM * DIM + c * DIM + k]
                        : Wr[(size_t)l * DIM * DIM + c * DIM + (k - DIM)];
    ushort_t hi = f2bf(w);
    float lo = w - bf2f(hi);
    W2[obase + kk] = hi;
    W2[obase + 4096 + kk] = f2bf(lo);  // part 1 offset = 4*1024
  }
}

// fp32 -> bf16 convert (input x)
__global__ void k_tobf16(const float* __restrict__ x, ushort_t* __restrict__ xb) {
  int i4 = blockIdx.x * blockDim.x + threadIdx.x;
  if (i4 >= N_NODES * DIM / 4) return;
  float4 v = ((const float4*)x)[i4];
  ushort4 o;
  o.x = f2bf(v.x);
  o.y = f2bf(v.y);
  o.z = f2bf(v.z);
  o.w = f2bf(v.w);
  ((ushort4*)xb)[i4] = o;
}

// ---------------- per-layer kernels ----------------

// one wave per node; lane holds 2 bf16 features (4 B); unroll x8.
__global__ void k_gather2(const ushort_t* __restrict__ xb, const int* __restrict__ row_ptr,
                          const int* __restrict__ col, const float* __restrict__ degf,
                          ushort_t* __restrict__ aggb) {
  int wid = threadIdx.x >> 6, lane = threadIdx.x & 63;
  int n = blockIdx.x * 4 + wid;
  if (n >= N_NODES) return;
  int beg = row_ptr[n], end = row_ptr[n + 1];
  const uint_t* x1 = (const uint_t*)xb;  // row = 64 uints
  float ax = 0.f, ay = 0.f;
  int p = beg;
  for (; p + 7 < end; p += 8) {
    int c[8];
#pragma unroll
    for (int u = 0; u < 8; ++u) c[u] = col[p + u];
    uint_t v[8];
#pragma unroll
    for (int u = 0; u < 8; ++u) v[u] = x1[c[u] * 64 + lane];
#pragma unroll
    for (int u = 0; u < 8; ++u) {
      ax += bf2f((ushort_t)(v[u] & 0xffffu));
      ay += bf2f((ushort_t)(v[u] >> 16));
    }
  }
  for (; p < end; ++p) {
    uint_t v = x1[col[p] * 64 + lane];
    ax += bf2f((ushort_t)(v & 0xffffu));
    ay += bf2f((ushort_t)(v >> 16));
  }
  float inv = 1.0f / degf[n];
  uint_t o = (uint_t)f2bf(ax * inv) | ((uint_t)f2bf(ay * inv) << 16);
  ((uint_t*)aggb)[n * 64 + lane] = o;
}

// MFMA GEMM: h[n][j] = bl[j] + sum_k A[n][k]*W[k][j], A=[aggb|xb] bf16, W=hi+lo bf16.
__global__ __launch_bounds__(256) void k_mfma(
    const ushort_t* __restrict__ aggb, const ushort_t* __restrict__ xb,
    const ushort_t* __restrict__ W2l, const float* __restrict__ bl,
    float* __restrict__ h) {
  __shared__ ushort_t Bs[8192];    // 16 KB: [part][q][c][8]
  __shared__ float Es[4][16][65];  // per-wave epilogue transpose

  int tid = threadIdx.x;
  int wave = tid >> 6, lane = tid & 63;
  int rw = blockIdx.x * 64 + wave * 16;
  int lr = lane & 15;  // frag row / frag col
  int q = lane >> 4;   // 0..3 (k-chunk)
  int rowA = rw + lr;
  if (rowA > N_NODES - 1) rowA = N_NODES - 1;  // clamp; stores guarded

  f32x4 acc[8];
#pragma unroll
  for (int c = 0; c < 8; ++c) acc[c] = (f32x4){0.f, 0.f, 0.f, 0.f};

#pragma unroll 1
  for (int ks = 0; ks < 8; ++ks) {
    const uint4* wsrc = (const uint4*)(W2l + (size_t)ks * 8192);
#pragma unroll
    for (int it = 0; it < 4; ++it) {
      int idx = it * 256 + tid;
      ((uint4*)Bs)[idx] = wsrc[idx];
    }
    __syncthreads();
    const ushort_t* Asrc = (ks < 4) ? aggb : xb;
    int koff = (ks & 3) * 32 + q * 8;
    bf16x8 af = *(const bf16x8*)(Asrc + (size_t)rowA * DIM + koff);
#pragma unroll
    for (int cf = 0; cf < 8; ++cf) {
      int ci = cf * 16 + lr;
      bf16x8 bh = *(const bf16x8*)(Bs + (q * 128 + ci) * 8);
      bf16x8 bo = *(const bf16x8*)(Bs + 4096 + (q * 128 + ci) * 8);
      acc[cf] = __builtin_amdgcn_mfma_f32_16x16x32_bf16(af, bh, acc[cf], 0, 0, 0);
      acc[cf] = __builtin_amdgcn_mfma_f32_16x16x32_bf16(af, bo, acc[cf], 0, 0, 0);
    }
    __syncthreads();
  }

  // epilogue: C frag (col=lane&15, row=q*4+i) -> LDS transpose -> coalesced store
#pragma unroll
  for (int colhalf = 0; colhalf < 2; ++colhalf) {
#pragma unroll
    for (int cf2 = 0; cf2 < 4; ++cf2) {
      f32x4 a = acc[colhalf * 4 + cf2];
#pragma unroll
      for (int i = 0; i < 4; ++i) Es[wave][q * 4 + i][cf2 * 16 + lr] = a[i];
    }
    __syncthreads();
#pragma unroll
    for (int it = 0; it < 4; ++it) {
      int idx = it * 64 + lane;
      int r = idx >> 4, c4 = idx & 15;
      int n = rw + r;
      if (n < N_NODES) {
        int j = colhalf * 64 + c4 * 4;
        float4 v = *(float4*)&Es[wave][r][c4 * 4];
        v.x += bl[j];
        v.y += bl[j + 1];
        v.z += bl[j + 2];
        v.w += bl[j + 3];
        *(float4*)(h + (size_t)n * DIM + j) = v;
      }
    }
    __syncthreads();
  }
}

__global__ void k_bn_stats(const float* __restrict__ h, float* __restrict__ sums) {
  int j = threadIdx.x;  // 128
  float s = 0.f, q = 0.f;
  for (int n = blockIdx.x; n < N_NODES; n += gridDim.x) {
    float v = h[n * DIM + j];
    s += v;
    q += v * v;
  }
  atomicAdd(&sums[j], s);
  atomicAdd(&sums[DIM + j], q);
}

// normalize + relu -> bf16
__global__ void k_bn_apply(const float* __restrict__ h, const float* __restrict__ sums,
                           const float* __restrict__ gamma, const float* __restrict__ beta,
                           ushort_t* __restrict__ xb) {
  int i4 = blockIdx.x * blockDim.x + threadIdx.x;
  if (i4 >= N_NODES * DIM / 4) return;
  int j0 = (i4 * 4) & (DIM - 1);
  float4 v = ((const float4*)h)[i4];
  float o[4] = {v.x, v.y, v.z, v.w};
  ushort4 r;
#pragma unroll
  for (int u = 0; u < 4; ++u) {
    int j = j0 + u;
    float mu = sums[j] * (1.0f / N_NODES);
    float var = sums[DIM + j] * (1.0f / N_NODES) - mu * mu;
    float sc = gamma[j] * rsqrtf(var + BN_EPS);
    o[u] = fmaxf((o[u] - mu) * sc + beta[j], 0.f);
  }
  r.x = f2bf(o[0]);
  r.y = f2bf(o[1]);
  r.z = f2bf(o[2]);
  r.w = f2bf(o[3]);
  ((ushort4*)xb)[i4] = r;
}

// ---------------- pooling + head ----------------

__global__ void k_gbounds(const int* __restrict__ batch, int* __restrict__ gstart) {
  int t = threadIdx.x;
  if (t > NGRAPHS) return;
  if (t == NGRAPHS) {
    gstart[NGRAPHS] = N_NODES;
    return;
  }
  int lo = 0, hi = N_NODES;
  while (lo < hi) {
    int mid = (lo + hi) >> 1;
    if (batch[mid] < t) lo = mid + 1;
    else hi = mid;
  }
  gstart[t] = lo;
}

__global__ void k_pool2(const ushort_t* __restrict__ xb, const int* __restrict__ gstart,
                        float* __restrict__ pooled) {
  int g = blockIdx.x >> 3;
  int ck = blockIdx.x & 7;
  int s = gstart[g], e = gstart[g + 1];
  int len = e - s;
  int per = (len + POOL_CHUNKS - 1) / POOL_CHUNKS;
  int rs = s + ck * per;
  int re = min(rs + per, e);
  int j2 = threadIdx.x & 63;  // uint (2 feats)
  int rg = threadIdx.x >> 6;  // 0..3
  const uint_t* x1 = (const uint_t*)xb;
  float ax = 0.f, ay = 0.f;
  for (int r = rs + rg; r < re; r += 4) {
    uint_t v = x1[(size_t)r * 64 + j2];
    ax += bf2f((ushort_t)(v & 0xffffu));
    ay += bf2f((ushort_t)(v >> 16));
  }
  __shared__ float sred[4][DIM];
  sred[rg][2 * j2] = ax;
  sred[rg][2 * j2 + 1] = ay;
  __syncthreads();
  if (rg < 2) {
    int j = rg * 64 + j2;
    float v = sred[0][j] + sred[1][j] + sred[2][j] + sred[3][j];
    atomicAdd(&pooled[g * DIM + j], v);
  }
}

// one block per graph: pm staged in LDS; 4 threads/hidden-unit, shuffle reduce;
// then 8 threads/class output.
__global__ void k_head2(const float* __restrict__ pooled, const int* __restrict__ gstart,
                        const float* __restrict__ W1, const float* __restrict__ b1,
                        const float* __restrict__ W2, const float* __restrict__ b2,
                        float* __restrict__ out) {
  int g = blockIdx.x;
  int tid = threadIdx.x;
  __shared__ float pm[DIM];
  __shared__ float hid[64];
  float inv = 1.0f / fmaxf((float)(gstart[g + 1] - gstart[g]), 1.0f);
  if (tid < DIM) pm[tid] = pooled[g * DIM + tid] * inv;
  __syncthreads();
  {
    int m = tid >> 2, part = tid & 3;  // 4 consecutive lanes per m
    const float* w = W1 + m * DIM + part * 32;
    const float* pp = pm + part * 32;
    float acc = 0.f;
#pragma unroll
    for (int k = 0; k < 32; ++k) acc += pp[k] * w[k];
    acc += __shfl_down(acc, 1);
    acc += __shfl_down(acc, 2);
    if (part == 0) hid[m] = fmaxf(acc + b1[m], 0.f);
  }
  __syncthreads();
  if (tid < NCLASSES * 8) {
    int c = tid >> 3, pp8 = tid & 7;  // 8 consecutive lanes per class
    const float* w = W2 + c * 64 + pp8 * 8;
    const float* hh = hid + pp8 * 8;
    float acc = 0.f;
#pragma unroll
    for (int k = 0; k < 8; ++k) acc += hh[k] * w[k];
    acc += __shfl_down(acc, 1);
    acc += __shfl_down(acc, 2);
    acc += __shfl_down(acc, 4);
    if (pp8 == 0) out[g * NCLASSES + c] = acc + b2[c];
  }
}

// ---------------- launch ----------------

extern "C" void kernel_launch(void* const* d_in, const int* in_sizes, int n_in,
                              void* d_out, int out_size, void* d_ws, size_t ws_size,
                              hipStream_t stream) {
  const float* x = (const float*)d_in[0];
  const int* edge = (const int*)d_in[1];
  const int* batch = (const int*)d_in[2];
  const float* Wl = (const float*)d_in[3];
  const float* bl = (const float*)d_in[4];
  const float* Wr = (const float*)d_in[5];
  const float* gamma = (const float*)d_in[6];
  const float* beta = (const float*)d_in[7];
  const float* W1 = (const float*)d_in[8];
  const float* b1 = (const float*)d_in[9];
  const float* W2 = (const float*)d_in[10];
  const float* b2 = (const float*)d_in[11];
  float* out = (float*)d_out;

  const int* src = edge;
  const int* dst = edge + N_EDGES;

  char* p = (char*)d_ws;
  auto alloc = [&](size_t bytes) -> void* {
    void* r = (void*)p;
    p += (bytes + 255) & ~(size_t)255;
    return r;
  };
  int* cnt = (int*)alloc(N_NODES * 4);
  int* incl = (int*)alloc(N_NODES * 4);
  int* bsum = (int*)alloc(SCAN_BLK * 4);
  int* boff = (int*)alloc(SCAN_BLK * 4);
  int* row_ptr = (int*)alloc((N_NODES + 1) * 4);
  int* cursor = (int*)alloc(N_NODES * 4);
  int* col = (int*)alloc(N_EDGES * 4);
  float* degf = (float*)alloc(N_NODES * 4);
  ushort_t* W2b = (ushort_t*)alloc((size_t)NLAYERS * 65536 * 2);
  ushort_t* xb0 = (ushort_t*)alloc((size_t)N_NODES * DIM * 2);
  ushort_t* xb_cur = (ushort_t*)alloc((size_t)N_NODES * DIM * 2);
  ushort_t* aggb = (ushort_t*)alloc((size_t)N_NODES * DIM * 2);
  float* hbuf = (float*)alloc((size_t)N_NODES * DIM * 4);
  float* sums = (float*)alloc(2 * DIM * 4);
  float* pooled = (float*)alloc(NGRAPHS * DIM * 4);
  int* gstart = (int*)alloc((NGRAPHS + 1) * 4);

  // ---- CSR build + weight prep + graph bounds + x->bf16 ----
  hipMemsetAsync(cnt, 0, N_NODES * 4, stream);
  k_count<<<(N_EDGES + 255) / 256, 256, 0, stream>>>(dst, cnt);
  k_scan_a<<<SCAN_NB, SCAN_BLK, 0, stream>>>(cnt, incl, bsum);
  k_scan_b<<<1, SCAN_BLK, 0, stream>>>(bsum, boff);
  k_scan_c<<<SCAN_NB, SCAN_BLK, 0, stream>>>(cnt, incl, boff, row_ptr, cursor, degf);
  k_fill<<<(N_EDGES + 255) / 256, 256, 0, stream>>>(src, dst, cursor, col);
  k_wt2<<<(NLAYERS * 8 * 4 * 128 + 255) / 256, 256, 0, stream>>>(Wl, Wr, W2b);
  k_gbounds<<<1, 128, 0, stream>>>(batch, gstart);
  k_tobf16<<<(N_NODES * DIM / 4 + 255) / 256, 256, 0, stream>>>(x, xb0);

  // ---- layers ----
  const ushort_t* xin = xb0;
  for (int l = 0; l < NLAYERS; ++l) {
    k_gather2<<<(N_NODES + 3) / 4, 256, 0, stream>>>(xin, row_ptr, col, degf, aggb);
    k_mfma<<<(N_NODES + 63) / 64, 256, 0, stream>>>(
        aggb, xin, W2b + (size_t)l * 65536, bl + (size_t)l * DIM, hbuf);
    hipMemsetAsync(sums, 0, 2 * DIM * 4, stream);
    k_bn_stats<<<512, DIM, 0, stream>>>(hbuf, sums);
    k_bn_apply<<<(N_NODES * DIM / 4 + 255) / 256, 256, 0, stream>>>(
        hbuf, sums, gamma + (size_t)l * DIM, beta + (size_t)l * DIM, xb_cur);
    xin = xb_cur;
  }

  // ---- pool + head ----
  hipMemsetAsync(pooled, 0, NGRAPHS * DIM * 4, stream);
  k_pool2<<<NGRAPHS * POOL_CHUNKS, 256, 0, stream>>>(xb_cur, gstart, pooled);
  k_head2<<<NGRAPHS, 256, 0, stream>>>(pooled, gstart, W1, b1, W2, b2, out);
}

// Round 8
// 377.017 us; speedup vs baseline: 3.1886x; 1.1278x over previous
//
#include <hip/hip_runtime.h>

#define N_NODES 50000
#define N_EDGES 800000
#define DIM 128
#define NLAYERS 3
#define NCLASSES 6
#define NGRAPHS 64
#define BN_EPS 1e-5f

#define SCAN_BLK 256
#define SCAN_NB ((N_NODES + SCAN_BLK - 1) / SCAN_BLK)  // 196

#define POOL_CHUNKS 8
#define NPART 16

typedef unsigned short ushort_t;
typedef unsigned int uint_t;
using bf16x8 = __attribute__((ext_vector_type(8))) short;
using f32x4 = __attribute__((ext_vector_type(4))) float;

__device__ __forceinline__ float bf2f(ushort_t b) {
  return __uint_as_float(((uint_t)b) << 16);
}
__device__ __forceinline__ ushort_t f2bf(float f) {  // round-to-nearest-even
  uint_t u = __float_as_uint(f);
  u += 0x7fffu + ((u >> 16) & 1u);
  return (ushort_t)(u >> 16);
}

// ---------------- CSR build ----------------

__global__ void k_count(const int* __restrict__ dst, int* __restrict__ cnt) {
  int e = blockIdx.x * blockDim.x + threadIdx.x;
  if (e < N_EDGES) atomicAdd(&cnt[dst[e]], 1);
}

__global__ void k_scan_a(const int* __restrict__ cnt, int* __restrict__ incl,
                         int* __restrict__ bsum) {
  __shared__ int s[SCAN_BLK];
  int i = blockIdx.x * SCAN_BLK + threadIdx.x;
  int v = (i < N_NODES) ? cnt[i] : 0;
  s[threadIdx.x] = v;
  __syncthreads();
  for (int off = 1; off < SCAN_BLK; off <<= 1) {
    int t = (threadIdx.x >= off) ? s[threadIdx.x - off] : 0;
    __syncthreads();
    s[threadIdx.x] += t;
    __syncthreads();
  }
  if (i < N_NODES) incl[i] = s[threadIdx.x];
  if (threadIdx.x == SCAN_BLK - 1) bsum[blockIdx.x] = s[SCAN_BLK - 1];
}

__global__ void k_scan_b(const int* __restrict__ bsum, int* __restrict__ boff) {
  __shared__ int s[SCAN_BLK];
  int t = threadIdx.x;
  int v = (t < SCAN_NB) ? bsum[t] : 0;
  s[t] = v;
  __syncthreads();
  for (int off = 1; off < SCAN_BLK; off <<= 1) {
    int u = (t >= off) ? s[t - off] : 0;
    __syncthreads();
    s[t] += u;
    __syncthreads();
  }
  boff[t] = s[t] - v;
}

__global__ void k_scan_c(const int* __restrict__ cnt, const int* __restrict__ incl,
                         const int* __restrict__ boff, int* __restrict__ row_ptr,
                         int* __restrict__ cursor, float* __restrict__ degf) {
  int i = blockIdx.x * SCAN_BLK + threadIdx.x;
  if (i < N_NODES) {
    int ex = incl[i] - cnt[i] + boff[blockIdx.x];
    row_ptr[i] = ex;
    cursor[i] = ex;
    degf[i] = (float)max(cnt[i], 1);
  }
  if (i == 0) row_ptr[N_NODES] = N_EDGES;
}

__global__ void k_fill(const int* __restrict__ src, const int* __restrict__ dst,
                       int* __restrict__ cursor, int* __restrict__ col) {
  int e = blockIdx.x * blockDim.x + threadIdx.x;
  if (e < N_EDGES) {
    int pos = atomicAdd(&cursor[dst[e]], 1);
    __builtin_nontemporal_store(src[e], &col[pos]);
  }
}

// ---------------- weight prep: split hi/lo bf16, frag-order permute ----------------
// W2 layout (ushort): [l][kstep 0..7][part 0..1][q 0..3][c 0..127][kk8 0..7]
__global__ void k_wt2(const float* __restrict__ Wl, const float* __restrict__ Wr,
                      ushort_t* __restrict__ W2) {
  int i = blockIdx.x * blockDim.x + threadIdx.x;  // 3*8*4*128 = 12288
  if (i >= NLAYERS * 8 * 4 * 128) return;
  int c = i & 127;
  int q = (i >> 7) & 3;
  int ks = (i >> 9) & 7;
  int l = i >> 12;
  int kbase = ks * 32 + q * 8;
  size_t obase = (size_t)l * 65536 + ks * 8192 + q * 1024 + c * 8;
#pragma unroll
  for (int kk = 0; kk < 8; ++kk) {
    int k = kbase + kk;
    float w = (k < DIM) ? Wl[(size_t)l * DIM * DIM + c * DIM + k]
                        : Wr[(size_t)l * DIM * DIM + c * DIM + (k - DIM)];
    ushort_t hi = f2bf(w);
    float lo = w - bf2f(hi);
    W2[obase + kk] = hi;
    W2[obase + 4096 + kk] = f2bf(lo);  // part 1 offset = 4*1024
  }
}

// fp32 -> bf16 convert (input x)
__global__ void k_tobf16(const float* __restrict__ x, ushort_t* __restrict__ xb) {
  int i4 = blockIdx.x * blockDim.x + threadIdx.x;
  if (i4 >= N_NODES * DIM / 4) return;
  float4 v = ((const float4*)x)[i4];
  ushort4 o;
  o.x = f2bf(v.x);
  o.y = f2bf(v.y);
  o.z = f2bf(v.z);
  o.w = f2bf(v.w);
  ((ushort4*)xb)[i4] = o;
}

// ---------------- per-layer kernels ----------------

// one wave per node; 16 lanes per row (uint4 = 16B), 4 neighbors concurrent,
// 4-deep unroll => 64B/lane in flight, 16 rows per wave-iteration.
__global__ void k_gather4(const ushort_t* __restrict__ xb, const int* __restrict__ row_ptr,
                          const int* __restrict__ col, const float* __restrict__ degf,
                          ushort_t* __restrict__ aggb) {
  int wid = threadIdx.x >> 6, lane = threadIdx.x & 63;
  int n = blockIdx.x * 4 + wid;
  if (n >= N_NODES) return;
  int beg = row_ptr[n], end = row_ptr[n + 1];
  int sub = lane >> 4;  // 0..3: neighbor sub-stream
  int c16 = lane & 15;  // uint4 index within row
  const uint4* x4 = (const uint4*)xb;
  float a[8] = {0.f, 0.f, 0.f, 0.f, 0.f, 0.f, 0.f, 0.f};
  int p = beg + sub;
  for (; p + 12 < end; p += 16) {
    int c[4];
#pragma unroll
    for (int u = 0; u < 4; ++u) c[u] = col[p + 4 * u];
    uint4 v[4];
#pragma unroll
    for (int u = 0; u < 4; ++u) v[u] = x4[(size_t)c[u] * 16 + c16];
#pragma unroll
    for (int u = 0; u < 4; ++u) {
      a[0] += bf2f((ushort_t)(v[u].x & 0xffffu));
      a[1] += bf2f((ushort_t)(v[u].x >> 16));
      a[2] += bf2f((ushort_t)(v[u].y & 0xffffu));
      a[3] += bf2f((ushort_t)(v[u].y >> 16));
      a[4] += bf2f((ushort_t)(v[u].z & 0xffffu));
      a[5] += bf2f((ushort_t)(v[u].z >> 16));
      a[6] += bf2f((ushort_t)(v[u].w & 0xffffu));
      a[7] += bf2f((ushort_t)(v[u].w >> 16));
    }
  }
  for (; p < end; p += 4) {
    uint4 v = x4[(size_t)col[p] * 16 + c16];
    a[0] += bf2f((ushort_t)(v.x & 0xffffu));
    a[1] += bf2f((ushort_t)(v.x >> 16));
    a[2] += bf2f((ushort_t)(v.y & 0xffffu));
    a[3] += bf2f((ushort_t)(v.y >> 16));
    a[4] += bf2f((ushort_t)(v.z & 0xffffu));
    a[5] += bf2f((ushort_t)(v.z >> 16));
    a[6] += bf2f((ushort_t)(v.w & 0xffffu));
    a[7] += bf2f((ushort_t)(v.w >> 16));
  }
#pragma unroll
  for (int u = 0; u < 8; ++u) {
    a[u] += __shfl_xor(a[u], 16);
    a[u] += __shfl_xor(a[u], 32);
  }
  if (sub == 0) {
    float inv = 1.0f / degf[n];
    uint4 o;
    o.x = (uint_t)f2bf(a[0] * inv) | ((uint_t)f2bf(a[1] * inv) << 16);
    o.y = (uint_t)f2bf(a[2] * inv) | ((uint_t)f2bf(a[3] * inv) << 16);
    o.z = (uint_t)f2bf(a[4] * inv) | ((uint_t)f2bf(a[5] * inv) << 16);
    o.w = (uint_t)f2bf(a[6] * inv) | ((uint_t)f2bf(a[7] * inv) << 16);
    ((uint4*)aggb)[(size_t)n * 16 + c16] = o;
  }
}

// MFMA GEMM + fused BN column stats.
__global__ __launch_bounds__(256) void k_mfma(
    const ushort_t* __restrict__ aggb, const ushort_t* __restrict__ xb,
    const ushort_t* __restrict__ W2l, const float* __restrict__ bl,
    float* __restrict__ h, float* __restrict__ sums_part) {
  __shared__ ushort_t Bs[8192];    // 16 KB: [part][q][c][8]
  __shared__ float Es[4][16][65];  // per-wave epilogue transpose
  __shared__ float lsums[256];     // [s:128][q:128]

  int tid = threadIdx.x;
  int wave = tid >> 6, lane = tid & 63;
  int rw = blockIdx.x * 64 + wave * 16;
  int lr = lane & 15;  // frag row / frag col
  int q = lane >> 4;   // 0..3 (k-chunk)
  int rowA = rw + lr;
  if (rowA > N_NODES - 1) rowA = N_NODES - 1;  // clamp; stores/stats guarded

  lsums[tid] = 0.f;

  f32x4 acc[8];
#pragma unroll
  for (int c = 0; c < 8; ++c) acc[c] = (f32x4){0.f, 0.f, 0.f, 0.f};

#pragma unroll 1
  for (int ks = 0; ks < 8; ++ks) {
    const uint4* wsrc = (const uint4*)(W2l + (size_t)ks * 8192);
#pragma unroll
    for (int it = 0; it < 4; ++it) {
      int idx = it * 256 + tid;
      ((uint4*)Bs)[idx] = wsrc[idx];
    }
    __syncthreads();
    const ushort_t* Asrc = (ks < 4) ? aggb : xb;
    int koff = (ks & 3) * 32 + q * 8;
    bf16x8 af = *(const bf16x8*)(Asrc + (size_t)rowA * DIM + koff);
#pragma unroll
    for (int cf = 0; cf < 8; ++cf) {
      int ci = cf * 16 + lr;
      bf16x8 bh = *(const bf16x8*)(Bs + (q * 128 + ci) * 8);
      bf16x8 bo = *(const bf16x8*)(Bs + 4096 + (q * 128 + ci) * 8);
      acc[cf] = __builtin_amdgcn_mfma_f32_16x16x32_bf16(af, bh, acc[cf], 0, 0, 0);
      acc[cf] = __builtin_amdgcn_mfma_f32_16x16x32_bf16(af, bo, acc[cf], 0, 0, 0);
    }
    __syncthreads();
  }

  // epilogue: C frag (col=lane&15, row=q*4+i) -> LDS transpose -> coalesced store
  float ts[2][4] = {{0.f, 0.f, 0.f, 0.f}, {0.f, 0.f, 0.f, 0.f}};
  float tq[2][4] = {{0.f, 0.f, 0.f, 0.f}, {0.f, 0.f, 0.f, 0.f}};
#pragma unroll
  for (int colhalf = 0; colhalf < 2; ++colhalf) {
#pragma unroll
    for (int cf2 = 0; cf2 < 4; ++cf2) {
      f32x4 a = acc[colhalf * 4 + cf2];
#pragma unroll
      for (int i = 0; i < 4; ++i) Es[wave][q * 4 + i][cf2 * 16 + lr] = a[i];
    }
    __syncthreads();
#pragma unroll
    for (int it = 0; it < 4; ++it) {
      int idx = it * 64 + lane;
      int r = idx >> 4, c4 = idx & 15;
      int n = rw + r;
      if (n < N_NODES) {
        int j = colhalf * 64 + c4 * 4;
        float4 v = *(float4*)&Es[wave][r][c4 * 4];
        v.x += bl[j];
        v.y += bl[j + 1];
        v.z += bl[j + 2];
        v.w += bl[j + 3];
        ts[colhalf][0] += v.x;
        ts[colhalf][1] += v.y;
        ts[colhalf][2] += v.z;
        ts[colhalf][3] += v.w;
        tq[colhalf][0] += v.x * v.x;
        tq[colhalf][1] += v.y * v.y;
        tq[colhalf][2] += v.z * v.z;
        tq[colhalf][3] += v.w * v.w;
        *(float4*)(h + (size_t)n * DIM + j) = v;
      }
    }
    __syncthreads();
  }
  // block-level BN partial reduce: LDS atomics, then one global atomic per thread
  {
    int c4 = lane & 15;
#pragma unroll
    for (int colhalf = 0; colhalf < 2; ++colhalf)
#pragma unroll
      for (int u = 0; u < 4; ++u) {
        int j = colhalf * 64 + c4 * 4 + u;
        atomicAdd(&lsums[j], ts[colhalf][u]);
        atomicAdd(&lsums[128 + j], tq[colhalf][u]);
      }
  }
  __syncthreads();
  atomicAdd(&sums_part[(blockIdx.x & (NPART - 1)) * 256 + tid], lsums[tid]);
}

// fold partitioned BN sums into per-feature scale/shift
__global__ void k_bnfin(const float* __restrict__ sums_part, const float* __restrict__ gamma,
                        const float* __restrict__ beta, float* __restrict__ bnsc) {
  int j = threadIdx.x;  // 128
  float s = 0.f, q = 0.f;
  for (int p = 0; p < NPART; ++p) {
    s += sums_part[p * 256 + j];
    q += sums_part[p * 256 + 128 + j];
  }
  float mu = s * (1.0f / N_NODES);
  float var = q * (1.0f / N_NODES) - mu * mu;
  float sc = gamma[j] * rsqrtf(var + BN_EPS);
  bnsc[j] = sc;
  bnsc[128 + j] = beta[j] - mu * sc;
}

// normalize + relu -> bf16
__global__ void k_bn_apply(const float* __restrict__ h, const float* __restrict__ bnsc,
                           ushort_t* __restrict__ xb) {
  int i4 = blockIdx.x * blockDim.x + threadIdx.x;
  if (i4 >= N_NODES * DIM / 4) return;
  int j0 = (i4 * 4) & (DIM - 1);
  float4 v = ((const float4*)h)[i4];
  float o[4] = {v.x, v.y, v.z, v.w};
  ushort4 r;
#pragma unroll
  for (int u = 0; u < 4; ++u) {
    int j = j0 + u;
    o[u] = fmaxf(fmaf(o[u], bnsc[j], bnsc[128 + j]), 0.f);
  }
  r.x = f2bf(o[0]);
  r.y = f2bf(o[1]);
  r.z = f2bf(o[2]);
  r.w = f2bf(o[3]);
  ((ushort4*)xb)[i4] = r;
}

// ---------------- pooling + head ----------------

__global__ void k_gbounds(const int* __restrict__ batch, int* __restrict__ gstart) {
  int t = threadIdx.x;
  if (t > NGRAPHS) return;
  if (t == NGRAPHS) {
    gstart[NGRAPHS] = N_NODES;
    return;
  }
  int lo = 0, hi = N_NODES;
  while (lo < hi) {
    int mid = (lo + hi) >> 1;
    if (batch[mid] < t) lo = mid + 1;
    else hi = mid;
  }
  gstart[t] = lo;
}

__global__ void k_pool2(const ushort_t* __restrict__ xb, const int* __restrict__ gstart,
                        float* __restrict__ pooled) {
  int g = blockIdx.x >> 3;
  int ck = blockIdx.x & 7;
  int s = gstart[g], e = gstart[g + 1];
  int len = e - s;
  int per = (len + POOL_CHUNKS - 1) / POOL_CHUNKS;
  int rs = s + ck * per;
  int re = min(rs + per, e);
  int j2 = threadIdx.x & 63;  // uint (2 feats)
  int rg = threadIdx.x >> 6;  // 0..3
  const uint_t* x1 = (const uint_t*)xb;
  float ax = 0.f, ay = 0.f;
  for (int r = rs + rg; r < re; r += 4) {
    uint_t v = x1[(size_t)r * 64 + j2];
    ax += bf2f((ushort_t)(v & 0xffffu));
    ay += bf2f((ushort_t)(v >> 16));
  }
  __shared__ float sred[4][DIM];
  sred[rg][2 * j2] = ax;
  sred[rg][2 * j2 + 1] = ay;
  __syncthreads();
  if (rg < 2) {
    int j = rg * 64 + j2;
    float v = sred[0][j] + sred[1][j] + sred[2][j] + sred[3][j];
    atomicAdd(&pooled[g * DIM + j], v);
  }
}

// one block per graph: pm staged in LDS; 4 threads/hidden-unit, shuffle reduce;
// then 8 threads/class output.
__global__ void k_head2(const float* __restrict__ pooled, const int* __restrict__ gstart,
                        const float* __restrict__ W1, const float* __restrict__ b1,
                        const float* __restrict__ W2, const float* __restrict__ b2,
                        float* __restrict__ out) {
  int g = blockIdx.x;
  int tid = threadIdx.x;
  __shared__ float pm[DIM];
  __shared__ float hid[64];
  float inv = 1.0f / fmaxf((float)(gstart[g + 1] - gstart[g]), 1.0f);
  if (tid < DIM) pm[tid] = pooled[g * DIM + tid] * inv;
  __syncthreads();
  {
    int m = tid >> 2, part = tid & 3;
    const float* w = W1 + m * DIM + part * 32;
    const float* pp = pm + part * 32;
    float acc = 0.f;
#pragma unroll
    for (int k = 0; k < 32; ++k) acc += pp[k] * w[k];
    acc += __shfl_down(acc, 1);
    acc += __shfl_down(acc, 2);
    if (part == 0) hid[m] = fmaxf(acc + b1[m], 0.f);
  }
  __syncthreads();
  if (tid < NCLASSES * 8) {
    int c = tid >> 3, pp8 = tid & 7;
    const float* w = W2 + c * 64 + pp8 * 8;
    const float* hh = hid + pp8 * 8;
    float acc = 0.f;
#pragma unroll
    for (int k = 0; k < 8; ++k) acc += hh[k] * w[k];
    acc += __shfl_down(acc, 1);
    acc += __shfl_down(acc, 2);
    acc += __shfl_down(acc, 4);
    if (pp8 == 0) out[g * NCLASSES + c] = acc + b2[c];
  }
}

// ---------------- launch ----------------

extern "C" void kernel_launch(void* const* d_in, const int* in_sizes, int n_in,
                              void* d_out, int out_size, void* d_ws, size_t ws_size,
                              hipStream_t stream) {
  const float* x = (const float*)d_in[0];
  const int* edge = (const int*)d_in[1];
  const int* batch = (const int*)d_in[2];
  const float* Wl = (const float*)d_in[3];
  const float* bl = (const float*)d_in[4];
  const float* Wr = (const float*)d_in[5];
  const float* gamma = (const float*)d_in[6];
  const float* beta = (const float*)d_in[7];
  const float* W1 = (const float*)d_in[8];
  const float* b1 = (const float*)d_in[9];
  const float* W2 = (const float*)d_in[10];
  const float* b2 = (const float*)d_in[11];
  float* out = (float*)d_out;

  const int* src = edge;
  const int* dst = edge + N_EDGES;

  char* p = (char*)d_ws;
  auto alloc = [&](size_t bytes) -> void* {
    void* r = (void*)p;
    p += (bytes + 255) & ~(size_t)255;
    return r;
  };
  int* cnt = (int*)alloc(N_NODES * 4);
  int* incl = (int*)alloc(N_NODES * 4);
  int* bsum = (int*)alloc(SCAN_BLK * 4);
  int* boff = (int*)alloc(SCAN_BLK * 4);
  int* row_ptr = (int*)alloc((N_NODES + 1) * 4);
  int* cursor = (int*)alloc(N_NODES * 4);
  int* col = (int*)alloc(N_EDGES * 4);
  float* degf = (float*)alloc(N_NODES * 4);
  ushort_t* W2b = (ushort_t*)alloc((size_t)NLAYERS * 65536 * 2);
  ushort_t* xb0 = (ushort_t*)alloc((size_t)N_NODES * DIM * 2);
  ushort_t* xb_cur = (ushort_t*)alloc((size_t)N_NODES * DIM * 2);
  ushort_t* aggb = (ushort_t*)alloc((size_t)N_NODES * DIM * 2);
  float* hbuf = (float*)alloc((size_t)N_NODES * DIM * 4);
  float* sums_part = (float*)alloc(NPART * 256 * 4);
  float* bnsc = (float*)alloc(2 * DIM * 4);
  float* pooled = (float*)alloc(NGRAPHS * DIM * 4);
  int* gstart = (int*)alloc((NGRAPHS + 1) * 4);

  // ---- CSR build + weight prep + graph bounds + x->bf16 ----
  hipMemsetAsync(cnt, 0, N_NODES * 4, stream);
  k_count<<<(N_EDGES + 255) / 256, 256, 0, stream>>>(dst, cnt);
  k_scan_a<<<SCAN_NB, SCAN_BLK, 0, stream>>>(cnt, incl, bsum);
  k_scan_b<<<1, SCAN_BLK, 0, stream>>>(bsum, boff);
  k_scan_c<<<SCAN_NB, SCAN_BLK, 0, stream>>>(cnt, incl, boff, row_ptr, cursor, degf);
  k_fill<<<(N_EDGES + 255) / 256, 256, 0, stream>>>(src, dst, cursor, col);
  k_wt2<<<(NLAYERS * 8 * 4 * 128 + 255) / 256, 256, 0, stream>>>(Wl, Wr, W2b);
  k_gbounds<<<1, 128, 0, stream>>>(batch, gstart);
  k_tobf16<<<(N_NODES * DIM / 4 + 255) / 256, 256, 0, stream>>>(x, xb0);

  // ---- layers ----
  const ushort_t* xin = xb0;
  for (int l = 0; l < NLAYERS; ++l) {
    k_gather4<<<(N_NODES + 3) / 4, 256, 0, stream>>>(xin, row_ptr, col, degf, aggb);
    hipMemsetAsync(sums_part, 0, NPART * 256 * 4, stream);
    k_mfma<<<(N_NODES + 63) / 64, 256, 0, stream>>>(
        aggb, xin, W2b + (size_t)l * 65536, bl + (size_t)l * DIM, hbuf, sums_part);
    k_bnfin<<<1, 128, 0, stream>>>(sums_part, gamma + (size_t)l * DIM,
                                   beta + (size_t)l * DIM, bnsc);
    k_bn_apply<<<(N_NODES * DIM / 4 + 255) / 256, 256, 0, stream>>>(hbuf, bnsc, xb_cur);
    xin = xb_cur;
  }

  // ---- pool + head ----
  hipMemsetAsync(pooled, 0, NGRAPHS * DIM * 4, stream);
  k_pool2<<<NGRAPHS * POOL_CHUNKS, 256, 0, stream>>>(xb_cur, gstart, pooled);
  k_head2<<<NGRAPHS, 256, 0, stream>>>(pooled, gstart, W1, b1, W2, b2, out);
}

// Round 9
// 358.828 us; speedup vs baseline: 3.3502x; 1.0507x over previous
//
#include <hip/hip_runtime.h>

#define N_NODES 50000
#define N_EDGES 800000
#define DIM 128
#define NLAYERS 3
#define NCLASSES 6
#define NGRAPHS 64
#define BN_EPS 1e-5f

#define SCAN_BLK 256
#define SCAN_NB ((N_NODES + SCAN_BLK - 1) / SCAN_BLK)  // 196

#define POOL_CHUNKS 8
#define NPART 16

#define FILL_GRPS 8
#define FILL_BPG 128                       // blocks per group; grid = 1024
#define NODES_PER_GRP ((N_NODES + FILL_GRPS - 1) / FILL_GRPS)  // 6250

typedef unsigned short ushort_t;
typedef unsigned int uint_t;
using bf16x8 = __attribute__((ext_vector_type(8))) short;
using f32x4 = __attribute__((ext_vector_type(4))) float;

__device__ __forceinline__ float bf2f(ushort_t b) {
  return __uint_as_float(((uint_t)b) << 16);
}
__device__ __forceinline__ ushort_t f2bf(float f) {  // round-to-nearest-even
  uint_t u = __float_as_uint(f);
  u += 0x7fffu + ((u >> 16) & 1u);
  return (ushort_t)(u >> 16);
}

// ---------------- CSR build ----------------

__global__ void k_count(const int* __restrict__ dst, int* __restrict__ cnt) {
  int e = blockIdx.x * blockDim.x + threadIdx.x;
  if (e < N_EDGES) atomicAdd(&cnt[dst[e]], 1);
}

__global__ void k_scan_a(const int* __restrict__ cnt, int* __restrict__ incl,
                         int* __restrict__ bsum) {
  __shared__ int s[SCAN_BLK];
  int i = blockIdx.x * SCAN_BLK + threadIdx.x;
  int v = (i < N_NODES) ? cnt[i] : 0;
  s[threadIdx.x] = v;
  __syncthreads();
  for (int off = 1; off < SCAN_BLK; off <<= 1) {
    int t = (threadIdx.x >= off) ? s[threadIdx.x - off] : 0;
    __syncthreads();
    s[threadIdx.x] += t;
    __syncthreads();
  }
  if (i < N_NODES) incl[i] = s[threadIdx.x];
  if (threadIdx.x == SCAN_BLK - 1) bsum[blockIdx.x] = s[SCAN_BLK - 1];
}

__global__ void k_scan_b(const int* __restrict__ bsum, int* __restrict__ boff) {
  __shared__ int s[SCAN_BLK];
  int t = threadIdx.x;
  int v = (t < SCAN_NB) ? bsum[t] : 0;
  s[t] = v;
  __syncthreads();
  for (int off = 1; off < SCAN_BLK; off <<= 1) {
    int u = (t >= off) ? s[t - off] : 0;
    __syncthreads();
    s[t] += u;
    __syncthreads();
  }
  boff[t] = s[t] - v;
}

__global__ void k_scan_c(const int* __restrict__ cnt, const int* __restrict__ incl,
                         const int* __restrict__ boff, int* __restrict__ row_ptr,
                         int* __restrict__ cursor, float* __restrict__ degf) {
  int i = blockIdx.x * SCAN_BLK + threadIdx.x;
  if (i < N_NODES) {
    int ex = incl[i] - cnt[i] + boff[blockIdx.x];
    row_ptr[i] = ex;
    cursor[i] = ex;
    degf[i] = (float)max(cnt[i], 1);
  }
  if (i == 0) row_ptr[N_NODES] = N_EDGES;
}

// XCD-partitioned fill: group g (= blockIdx & 7, presumed XCD) owns nodes
// [g*6250, g*6250+6250); its blocks scan all edges and keep only theirs, so
// each col cache line is written from a single XCD L2 (no cross-XCD ping-pong).
__global__ void k_fill2(const int* __restrict__ src, const int* __restrict__ dst,
                        int* __restrict__ cursor, int* __restrict__ col) {
  int grp = blockIdx.x & (FILL_GRPS - 1);
  int blk = blockIdx.x >> 3;
  int lo = grp * NODES_PER_GRP;
  int hi = min(lo + NODES_PER_GRP, N_NODES);
  int per = (N_EDGES + FILL_BPG - 1) / FILL_BPG;  // 6250
  int es = blk * per, ee = min(es + per, N_EDGES);
  for (int e = es + (int)threadIdx.x; e < ee; e += (int)blockDim.x) {
    int d = dst[e];
    if (d >= lo && d < hi) {
      int pos = atomicAdd(&cursor[d], 1);
      col[pos] = src[e];
    }
  }
}

// ---------------- weight prep: split hi/lo bf16, frag-order permute ----------------
// W2 layout (ushort): [l][kstep 0..7][part 0..1][q 0..3][c 0..127][kk8 0..7]
__global__ void k_wt2(const float* __restrict__ Wl, const float* __restrict__ Wr,
                      ushort_t* __restrict__ W2) {
  int i = blockIdx.x * blockDim.x + threadIdx.x;  // 3*8*4*128 = 12288
  if (i >= NLAYERS * 8 * 4 * 128) return;
  int c = i & 127;
  int q = (i >> 7) & 3;
  int ks = (i >> 9) & 7;
  int l = i >> 12;
  int kbase = ks * 32 + q * 8;
  size_t obase = (size_t)l * 65536 + ks * 8192 + q * 1024 + c * 8;
#pragma unroll
  for (int kk = 0; kk < 8; ++kk) {
    int k = kbase + kk;
    float w = (k < DIM) ? Wl[(size_t)l * DIM * DIM + c * DIM + k]
                        : Wr[(size_t)l * DIM * DIM + c * DIM + (k - DIM)];
    ushort_t hi = f2bf(w);
    float lo = w - bf2f(hi);
    W2[obase + kk] = hi;
    W2[obase + 4096 + kk] = f2bf(lo);  // part 1 offset = 4*1024
  }
}

// fp32 -> bf16 convert (input x)
__global__ void k_tobf16(const float* __restrict__ x, ushort_t* __restrict__ xb) {
  int i4 = blockIdx.x * blockDim.x + threadIdx.x;
  if (i4 >= N_NODES * DIM / 4) return;
  float4 v = ((const float4*)x)[i4];
  ushort4 o;
  o.x = f2bf(v.x);
  o.y = f2bf(v.y);
  o.z = f2bf(v.z);
  o.w = f2bf(v.w);
  ((ushort4*)xb)[i4] = o;
}

// ---------------- per-layer kernels ----------------

// one wave per node; 16 lanes per row (uint4 = 16B), 4 neighbors concurrent,
// 4-deep unroll => 64B/lane in flight, 16 rows per wave-iteration.
__global__ void k_gather4(const ushort_t* __restrict__ xb, const int* __restrict__ row_ptr,
                          const int* __restrict__ col, const float* __restrict__ degf,
                          ushort_t* __restrict__ aggb) {
  int wid = threadIdx.x >> 6, lane = threadIdx.x & 63;
  int n = blockIdx.x * 4 + wid;
  if (n >= N_NODES) return;
  int beg = row_ptr[n], end = row_ptr[n + 1];
  int sub = lane >> 4;  // 0..3: neighbor sub-stream
  int c16 = lane & 15;  // uint4 index within row
  const uint4* x4 = (const uint4*)xb;
  float a[8] = {0.f, 0.f, 0.f, 0.f, 0.f, 0.f, 0.f, 0.f};
  int p = beg + sub;
  for (; p + 12 < end; p += 16) {
    int c[4];
#pragma unroll
    for (int u = 0; u < 4; ++u) c[u] = col[p + 4 * u];
    uint4 v[4];
#pragma unroll
    for (int u = 0; u < 4; ++u) v[u] = x4[(size_t)c[u] * 16 + c16];
#pragma unroll
    for (int u = 0; u < 4; ++u) {
      a[0] += bf2f((ushort_t)(v[u].x & 0xffffu));
      a[1] += bf2f((ushort_t)(v[u].x >> 16));
      a[2] += bf2f((ushort_t)(v[u].y & 0xffffu));
      a[3] += bf2f((ushort_t)(v[u].y >> 16));
      a[4] += bf2f((ushort_t)(v[u].z & 0xffffu));
      a[5] += bf2f((ushort_t)(v[u].z >> 16));
      a[6] += bf2f((ushort_t)(v[u].w & 0xffffu));
      a[7] += bf2f((ushort_t)(v[u].w >> 16));
    }
  }
  for (; p < end; p += 4) {
    uint4 v = x4[(size_t)col[p] * 16 + c16];
    a[0] += bf2f((ushort_t)(v.x & 0xffffu));
    a[1] += bf2f((ushort_t)(v.x >> 16));
    a[2] += bf2f((ushort_t)(v.y & 0xffffu));
    a[3] += bf2f((ushort_t)(v.y >> 16));
    a[4] += bf2f((ushort_t)(v.z & 0xffffu));
    a[5] += bf2f((ushort_t)(v.z >> 16));
    a[6] += bf2f((ushort_t)(v.w & 0xffffu));
    a[7] += bf2f((ushort_t)(v.w >> 16));
  }
#pragma unroll
  for (int u = 0; u < 8; ++u) {
    a[u] += __shfl_xor(a[u], 16);
    a[u] += __shfl_xor(a[u], 32);
  }
  if (sub == 0) {
    float inv = 1.0f / degf[n];
    uint4 o;
    o.x = (uint_t)f2bf(a[0] * inv) | ((uint_t)f2bf(a[1] * inv) << 16);
    o.y = (uint_t)f2bf(a[2] * inv) | ((uint_t)f2bf(a[3] * inv) << 16);
    o.z = (uint_t)f2bf(a[4] * inv) | ((uint_t)f2bf(a[5] * inv) << 16);
    o.w = (uint_t)f2bf(a[6] * inv) | ((uint_t)f2bf(a[7] * inv) << 16);
    ((uint4*)aggb)[(size_t)n * 16 + c16] = o;
  }
}

// MFMA GEMM + fused BN column stats.
__global__ __launch_bounds__(256) void k_mfma(
    const ushort_t* __restrict__ aggb, const ushort_t* __restrict__ xb,
    const ushort_t* __restrict__ W2l, const float* __restrict__ bl,
    float* __restrict__ h, float* __restrict__ sums_part) {
  __shared__ ushort_t Bs[8192];    // 16 KB: [part][q][c][8]
  __shared__ float Es[4][16][65];  // per-wave epilogue transpose
  __shared__ float lsums[256];     // [s:128][q:128]

  int tid = threadIdx.x;
  int wave = tid >> 6, lane = tid & 63;
  int rw = blockIdx.x * 64 + wave * 16;
  int lr = lane & 15;  // frag row / frag col
  int q = lane >> 4;   // 0..3 (k-chunk)
  int rowA = rw + lr;
  if (rowA > N_NODES - 1) rowA = N_NODES - 1;  // clamp; stores/stats guarded

  lsums[tid] = 0.f;

  f32x4 acc[8];
#pragma unroll
  for (int c = 0; c < 8; ++c) acc[c] = (f32x4){0.f, 0.f, 0.f, 0.f};

#pragma unroll 1
  for (int ks = 0; ks < 8; ++ks) {
    const uint4* wsrc = (const uint4*)(W2l + (size_t)ks * 8192);
#pragma unroll
    for (int it = 0; it < 4; ++it) {
      int idx = it * 256 + tid;
      ((uint4*)Bs)[idx] = wsrc[idx];
    }
    __syncthreads();
    const ushort_t* Asrc = (ks < 4) ? aggb : xb;
    int koff = (ks & 3) * 32 + q * 8;
    bf16x8 af = *(const bf16x8*)(Asrc + (size_t)rowA * DIM + koff);
#pragma unroll
    for (int cf = 0; cf < 8; ++cf) {
      int ci = cf * 16 + lr;
      bf16x8 bh = *(const bf16x8*)(Bs + (q * 128 + ci) * 8);
      bf16x8 bo = *(const bf16x8*)(Bs + 4096 + (q * 128 + ci) * 8);
      acc[cf] = __builtin_amdgcn_mfma_f32_16x16x32_bf16(af, bh, acc[cf], 0, 0, 0);
      acc[cf] = __builtin_amdgcn_mfma_f32_16x16x32_bf16(af, bo, acc[cf], 0, 0, 0);
    }
    __syncthreads();
  }

  // epilogue: C frag (col=lane&15, row=q*4+i) -> LDS transpose -> coalesced store
  float ts[2][4] = {{0.f, 0.f, 0.f, 0.f}, {0.f, 0.f, 0.f, 0.f}};
  float tq[2][4] = {{0.f, 0.f, 0.f, 0.f}, {0.f, 0.f, 0.f, 0.f}};
#pragma unroll
  for (int colhalf = 0; colhalf < 2; ++colhalf) {
#pragma unroll
    for (int cf2 = 0; cf2 < 4; ++cf2) {
      f32x4 a = acc[colhalf * 4 + cf2];
#pragma unroll
      for (int i = 0; i < 4; ++i) Es[wave][q * 4 + i][cf2 * 16 + lr] = a[i];
    }
    __syncthreads();
#pragma unroll
    for (int it = 0; it < 4; ++it) {
      int idx = it * 64 + lane;
      int r = idx >> 4, c4 = idx & 15;
      int n = rw + r;
      if (n < N_NODES) {
        int j = colhalf * 64 + c4 * 4;
        float4 v = *(float4*)&Es[wave][r][c4 * 4];
        v.x += bl[j];
        v.y += bl[j + 1];
        v.z += bl[j + 2];
        v.w += bl[j + 3];
        ts[colhalf][0] += v.x;
        ts[colhalf][1] += v.y;
        ts[colhalf][2] += v.z;
        ts[colhalf][3] += v.w;
        tq[colhalf][0] += v.x * v.x;
        tq[colhalf][1] += v.y * v.y;
        tq[colhalf][2] += v.z * v.z;
        tq[colhalf][3] += v.w * v.w;
        *(float4*)(h + (size_t)n * DIM + j) = v;
      }
    }
    __syncthreads();
  }
  // block-level BN partial reduce: LDS atomics, then one global atomic per thread
  {
    int c4 = lane & 15;
#pragma unroll
    for (int colhalf = 0; colhalf < 2; ++colhalf)
#pragma unroll
      for (int u = 0; u < 4; ++u) {
        int j = colhalf * 64 + c4 * 4 + u;
        atomicAdd(&lsums[j], ts[colhalf][u]);
        atomicAdd(&lsums[128 + j], tq[colhalf][u]);
      }
  }
  __syncthreads();
  atomicAdd(&sums_part[(blockIdx.x & (NPART - 1)) * 256 + tid], lsums[tid]);
}

// fold partitioned BN sums into per-feature scale/shift
__global__ void k_bnfin(const float* __restrict__ sums_part, const float* __restrict__ gamma,
                        const float* __restrict__ beta, float* __restrict__ bnsc) {
  int j = threadIdx.x;  // 128
  float s = 0.f, q = 0.f;
  for (int p = 0; p < NPART; ++p) {
    s += sums_part[p * 256 + j];
    q += sums_part[p * 256 + 128 + j];
  }
  float mu = s * (1.0f / N_NODES);
  float var = q * (1.0f / N_NODES) - mu * mu;
  float sc = gamma[j] * rsqrtf(var + BN_EPS);
  bnsc[j] = sc;
  bnsc[128 + j] = beta[j] - mu * sc;
}

// normalize + relu -> bf16
__global__ void k_bn_apply(const float* __restrict__ h, const float* __restrict__ bnsc,
                           ushort_t* __restrict__ xb) {
  int i4 = blockIdx.x * blockDim.x + threadIdx.x;
  if (i4 >= N_NODES * DIM / 4) return;
  int j0 = (i4 * 4) & (DIM - 1);
  float4 v = ((const float4*)h)[i4];
  float o[4] = {v.x, v.y, v.z, v.w};
  ushort4 r;
#pragma unroll
  for (int u = 0; u < 4; ++u) {
    int j = j0 + u;
    o[u] = fmaxf(fmaf(o[u], bnsc[j], bnsc[128 + j]), 0.f);
  }
  r.x = f2bf(o[0]);
  r.y = f2bf(o[1]);
  r.z = f2bf(o[2]);
  r.w = f2bf(o[3]);
  ((ushort4*)xb)[i4] = r;
}

// ---------------- pooling + head ----------------

__global__ void k_gbounds(const int* __restrict__ batch, int* __restrict__ gstart) {
  int t = threadIdx.x;
  if (t > NGRAPHS) return;
  if (t == NGRAPHS) {
    gstart[NGRAPHS] = N_NODES;
    return;
  }
  int lo = 0, hi = N_NODES;
  while (lo < hi) {
    int mid = (lo + hi) >> 1;
    if (batch[mid] < t) lo = mid + 1;
    else hi = mid;
  }
  gstart[t] = lo;
}

// pool over the LAST layer directly from fp32 h + bnsc (BN+ReLU fused in).
__global__ void k_pool3(const float* __restrict__ h, const float* __restrict__ bnsc,
                        const int* __restrict__ gstart, float* __restrict__ pooled) {
  int g = blockIdx.x >> 3;
  int ck = blockIdx.x & 7;
  int s = gstart[g], e = gstart[g + 1];
  int len = e - s;
  int per = (len + POOL_CHUNKS - 1) / POOL_CHUNKS;
  int rs = s + ck * per;
  int re = min(rs + per, e);
  int j = threadIdx.x & 127;  // feature
  int rg = threadIdx.x >> 7;  // 0..1
  float sc = bnsc[j], sh = bnsc[128 + j];
  float acc = 0.f;
  for (int r = rs + rg; r < re; r += 2)
    acc += fmaxf(fmaf(h[(size_t)r * DIM + j], sc, sh), 0.f);
  __shared__ float sred[2][DIM];
  sred[rg][j] = acc;
  __syncthreads();
  if (rg == 0) atomicAdd(&pooled[g * DIM + j], sred[0][j] + sred[1][j]);
}

// one block per graph: pm staged in LDS; 4 threads/hidden-unit, shuffle reduce;
// then 8 threads/class output.
__global__ void k_head2(const float* __restrict__ pooled, const int* __restrict__ gstart,
                        const float* __restrict__ W1, const float* __restrict__ b1,
                        const float* __restrict__ W2, const float* __restrict__ b2,
                        float* __restrict__ out) {
  int g = blockIdx.x;
  int tid = threadIdx.x;
  __shared__ float pm[DIM];
  __shared__ float hid[64];
  float inv = 1.0f / fmaxf((float)(gstart[g + 1] - gstart[g]), 1.0f);
  if (tid < DIM) pm[tid] = pooled[g * DIM + tid] * inv;
  __syncthreads();
  {
    int m = tid >> 2, part = tid & 3;
    const float* w = W1 + m * DIM + part * 32;
    const float* pp = pm + part * 32;
    float acc = 0.f;
#pragma unroll
    for (int k = 0; k < 32; ++k) acc += pp[k] * w[k];
    acc += __shfl_down(acc, 1);
    acc += __shfl_down(acc, 2);
    if (part == 0) hid[m] = fmaxf(acc + b1[m], 0.f);
  }
  __syncthreads();
  if (tid < NCLASSES * 8) {
    int c = tid >> 3, pp8 = tid & 7;
    const float* w = W2 + c * 64 + pp8 * 8;
    const float* hh = hid + pp8 * 8;
    float acc = 0.f;
#pragma unroll
    for (int k = 0; k < 8; ++k) acc += hh[k] * w[k];
    acc += __shfl_down(acc, 1);
    acc += __shfl_down(acc, 2);
    acc += __shfl_down(acc, 4);
    if (pp8 == 0) out[g * NCLASSES + c] = acc + b2[c];
  }
}

// ---------------- launch ----------------

extern "C" void kernel_launch(void* const* d_in, const int* in_sizes, int n_in,
                              void* d_out, int out_size, void* d_ws, size_t ws_size,
                              hipStream_t stream) {
  const float* x = (const float*)d_in[0];
  const int* edge = (const int*)d_in[1];
  const int* batch = (const int*)d_in[2];
  const float* Wl = (const float*)d_in[3];
  const float* bl = (const float*)d_in[4];
  const float* Wr = (const float*)d_in[5];
  const float* gamma = (const float*)d_in[6];
  const float* beta = (const float*)d_in[7];
  const float* W1 = (const float*)d_in[8];
  const float* b1 = (const float*)d_in[9];
  const float* W2 = (const float*)d_in[10];
  const float* b2 = (const float*)d_in[11];
  float* out = (float*)d_out;

  const int* src = edge;
  const int* dst = edge + N_EDGES;

  char* p = (char*)d_ws;
  auto alloc = [&](size_t bytes) -> void* {
    void* r = (void*)p;
    p += (bytes + 255) & ~(size_t)255;
    return r;
  };
  int* cnt = (int*)alloc(N_NODES * 4);
  int* incl = (int*)alloc(N_NODES * 4);
  int* bsum = (int*)alloc(SCAN_BLK * 4);
  int* boff = (int*)alloc(SCAN_BLK * 4);
  int* row_ptr = (int*)alloc((N_NODES + 1) * 4);
  int* cursor = (int*)alloc(N_NODES * 4);
  int* col = (int*)alloc(N_EDGES * 4);
  float* degf = (float*)alloc(N_NODES * 4);
  ushort_t* W2b = (ushort_t*)alloc((size_t)NLAYERS * 65536 * 2);
  ushort_t* xb0 = (ushort_t*)alloc((size_t)N_NODES * DIM * 2);
  ushort_t* xb_cur = (ushort_t*)alloc((size_t)N_NODES * DIM * 2);
  ushort_t* aggb = (ushort_t*)alloc((size_t)N_NODES * DIM * 2);
  float* hbuf = (float*)alloc((size_t)N_NODES * DIM * 4);
  float* sums_part = (float*)alloc(NPART * 256 * 4);
  float* bnsc = (float*)alloc(2 * DIM * 4);
  float* pooled = (float*)alloc(NGRAPHS * DIM * 4);
  int* gstart = (int*)alloc((NGRAPHS + 1) * 4);

  // ---- CSR build + weight prep + graph bounds + x->bf16 ----
  hipMemsetAsync(cnt, 0, N_NODES * 4, stream);
  k_count<<<(N_EDGES + 255) / 256, 256, 0, stream>>>(dst, cnt);
  k_scan_a<<<SCAN_NB, SCAN_BLK, 0, stream>>>(cnt, incl, bsum);
  k_scan_b<<<1, SCAN_BLK, 0, stream>>>(bsum, boff);
  k_scan_c<<<SCAN_NB, SCAN_BLK, 0, stream>>>(cnt, incl, boff, row_ptr, cursor, degf);
  k_fill2<<<FILL_GRPS * FILL_BPG, 256, 0, stream>>>(src, dst, cursor, col);
  k_wt2<<<(NLAYERS * 8 * 4 * 128 + 255) / 256, 256, 0, stream>>>(Wl, Wr, W2b);
  k_gbounds<<<1, 128, 0, stream>>>(batch, gstart);
  k_tobf16<<<(N_NODES * DIM / 4 + 255) / 256, 256, 0, stream>>>(x, xb0);

  // ---- layers ----
  const ushort_t* xin = xb0;
  for (int l = 0; l < NLAYERS; ++l) {
    k_gather4<<<(N_NODES + 3) / 4, 256, 0, stream>>>(xin, row_ptr, col, degf, aggb);
    hipMemsetAsync(sums_part, 0, NPART * 256 * 4, stream);
    k_mfma<<<(N_NODES + 63) / 64, 256, 0, stream>>>(
        aggb, xin, W2b + (size_t)l * 65536, bl + (size_t)l * DIM, hbuf, sums_part);
    k_bnfin<<<1, 128, 0, stream>>>(sums_part, gamma + (size_t)l * DIM,
                                   beta + (size_t)l * DIM, bnsc);
    if (l < NLAYERS - 1) {
      k_bn_apply<<<(N_NODES * DIM / 4 + 255) / 256, 256, 0, stream>>>(hbuf, bnsc, xb_cur);
      xin = xb_cur;
    }
  }

  // ---- pool (BN+ReLU fused) + head ----
  hipMemsetAsync(pooled, 0, NGRAPHS * DIM * 4, stream);
  k_pool3<<<NGRAPHS * POOL_CHUNKS, 256, 0, stream>>>(hbuf, bnsc, gstart, pooled);
  k_head2<<<NGRAPHS, 256, 0, stream>>>(pooled, gstart, W1, b1, W2, b2, out);
}